// Round 7
// baseline (965.226 us; speedup 1.0000x reference)
//
#include <hip/hip_runtime.h>
#include <hip/hip_bf16.h>

#define NTOK 2048
#define EMBED 512
#define NHEADS 8
#define HD 64
#define NBINS 512
#define MAXSEL 256

typedef unsigned short u16;
typedef unsigned int u32;

__device__ __forceinline__ float lof(u32 u){ return __uint_as_float(u << 16); }
__device__ __forceinline__ float hif(u32 u){ return __uint_as_float(u & 0xffff0000u); }
__device__ __forceinline__ float bf2f(u16 u){ return __uint_as_float(((u32)u) << 16); }
__device__ __forceinline__ u16 f2b(float f){
    __hip_bfloat16 h = __float2bfloat16(f);
    return *(u16*)&h;
}
__device__ __forceinline__ u32 pack2(float lo, float hi){
    return (u32)f2b(lo) | ((u32)f2b(hi) << 16);
}

__device__ __forceinline__ void fma8(const float* x, u32 ux, u32 uy, u32 uz, u32 uw, float& a){
    a += x[0]*lof(ux) + x[1]*hif(ux) + x[2]*lof(uy) + x[3]*hif(uy)
       + x[4]*lof(uz) + x[5]*hif(uz) + x[6]*lof(uw) + x[7]*hif(uw);
}
__device__ __forceinline__ void fma4f(const float* x, float4 w, float& a){
    a += x[0]*w.x + x[1]*w.y + x[2]*w.z + x[3]*w.w;
}

// ============ K0: per-tensor dtype sniff ============
// grid(12) blocks x 64 threads. Block i samples tensor i's even u16s as bf16.
// f32 data -> even u16s are low mantissa bits -> random bf16 exponent -> max >> 100.
// bf16 data here (N(0,1) or scaled) -> max < 10. flags[i] = 1 means f32.
__global__ __launch_bounds__(64) void sniff_kernel(
    const void* p0, const void* p1, const void* p2, const void* p3,
    const void* p4, const void* p5, const void* p6, const void* p7,
    const void* p8, const void* p9, const void* p10, const void* p11,
    u32* flags)
{
    const void* ps[12] = {p0,p1,p2,p3,p4,p5,p6,p7,p8,p9,p10,p11};
    const u16* p = (const u16*)ps[blockIdx.x];
    __shared__ float red[64];
    int lane = threadIdx.x;
    float m = 0.f;
    #pragma unroll
    for (int k=0; k<4; k++){
        int idx = lane*4 + k;              // 0..255 -> u16 index 0..510 (min tensor = 512 elems)
        float v = fabsf(bf2f(p[2*idx]));
        m = fmaxf(m, v);                   // fmaxf drops NaN samples; finite huge ones remain
    }
    red[lane] = m;
    __syncthreads();
    for (int off=32; off; off>>=1){
        if (lane < off) red[lane] = fmaxf(red[lane], red[lane+off]);
        __syncthreads();
    }
    if (lane == 0) flags[blockIdx.x] = (red[0] > 100.f) ? 1u : 0u;
}

// ============ K1: K/V projection (+ per-head L2 norm + centroid bin for K) ============
// grid (512, 2), block 256. 4 tokens per block. y: 0=K, 1=V.
// Bins from f32 projections (argmax_c<k,c> == argmax_c<kn,c>, positive scale).
__global__ __launch_bounds__(256) void projkv_kernel(
    const void* __restrict__ Xk, const void* __restrict__ Xv,
    const void* __restrict__ Wk, const void* __restrict__ bk,
    const void* __restrict__ Wv, const void* __restrict__ bv,
    const void* __restrict__ cen, const u32* __restrict__ flags,
    u16* __restrict__ Kb, u16* __restrict__ Vb, u16* __restrict__ kbin)
{
    int which = blockIdx.y;                // 0=K, 1=V
    const void* X  = which ? Xv : Xk;
    const void* W  = which ? Wv : Wk;
    const void* bb = which ? bv : bk;
    const u32 fx = which ? flags[2] : flags[1];
    const u32 fw = which ? flags[7] : flags[5];
    const u32 fb = which ? flags[8] : flags[6];
    const u32 fc = flags[11];
    u16* OutB = which ? Vb : Kb;
    int r0 = blockIdx.x * 4;
    int t = threadIdx.x;

    __shared__ float xs[4][512];
    __shared__ float ps[32][8];
    __shared__ float invn[32];
    __shared__ float bvs[32][8];
    __shared__ int   bis[32][8];

    // stage X rows (4 x 512 elems; thread t does flat elements t*8..t*8+7)
    {
        float* xr = &xs[0][0] + t*8;
        if (!fx){
            uint4 u = ((const uint4*)((const u16*)X + (size_t)r0*EMBED))[t];
            xr[0]=lof(u.x); xr[1]=hif(u.x); xr[2]=lof(u.y); xr[3]=hif(u.y);
            xr[4]=lof(u.z); xr[5]=hif(u.z); xr[6]=lof(u.w); xr[7]=hif(u.w);
        } else {
            const float4* X4 = (const float4*)((const float*)X + (size_t)r0*EMBED);
            float4 fa = X4[2*t], fb2 = X4[2*t+1];
            xr[0]=fa.x; xr[1]=fa.y; xr[2]=fa.z; xr[3]=fa.w;
            xr[4]=fb2.x; xr[5]=fb2.y; xr[6]=fb2.z; xr[7]=fb2.w;
        }
    }
    __syncthreads();

    // GEMM: thread t computes cols {t, t+256} for 4 rows
    float a0[4] = {0.f,0.f,0.f,0.f};
    float a1[4] = {0.f,0.f,0.f,0.f};
    if (!fw){
        const uint4* wr0 = (const uint4*)((const u16*)W + (size_t)t*EMBED);
        const uint4* wr1 = (const uint4*)((const u16*)W + (size_t)(t+256)*EMBED);
        for (int i8=0; i8<64; i8++){
            uint4 w0 = wr0[i8];
            uint4 w1 = wr1[i8];
            #pragma unroll
            for (int r=0; r<4; r++){
                const float* x = &xs[r][i8*8];
                fma8(x, w0.x, w0.y, w0.z, w0.w, a0[r]);
                fma8(x, w1.x, w1.y, w1.z, w1.w, a1[r]);
            }
        }
    } else {
        const float4* wr0 = (const float4*)((const float*)W + (size_t)t*EMBED);
        const float4* wr1 = (const float4*)((const float*)W + (size_t)(t+256)*EMBED);
        for (int i4=0; i4<128; i4++){
            float4 w0 = wr0[i4];
            float4 w1 = wr1[i4];
            #pragma unroll
            for (int r=0; r<4; r++){
                const float* x = &xs[r][i4*4];
                fma4f(x, w0, a0[r]);
                fma4f(x, w1, a1[r]);
            }
        }
    }
    {
        float b0 = fb ? ((const float*)bb)[t]     : bf2f(((const u16*)bb)[t]);
        float b1 = fb ? ((const float*)bb)[t+256] : bf2f(((const u16*)bb)[t+256]);
        #pragma unroll
        for (int r=0; r<4; r++){ a0[r]+=b0; a1[r]+=b1; }
    }
    __syncthreads();                       // all xs reads done, reuse for projections
    #pragma unroll
    for (int r=0; r<4; r++){ xs[r][t]=a0[r]; xs[r][t+256]=a1[r]; }
    __syncthreads();

    if (which == 1){
        // V: store raw bf16 (thread t packs 8 consecutive elems)
        int idx = t*8, row = idx>>9, col = idx&511;
        const float* x = &xs[row][col];
        uint4 v;
        v.x = pack2(x[0],x[1]); v.y = pack2(x[2],x[3]);
        v.z = pack2(x[4],x[5]); v.w = pack2(x[6],x[7]);
        ((uint4*)(OutB + (size_t)r0*EMBED))[t] = v;
        return;
    }

    // per-head sumsq: 32 head-rows (4 tokens x 8 heads), 8 threads each
    int hr = t>>3, part = t&7;
    int row = hr>>3, head = hr&7;
    {
        const float* pr = &xs[row][head*HD + part*8];
        float ss = 0.f;
        #pragma unroll
        for (int d=0; d<8; d++) ss += pr[d]*pr[d];
        ps[hr][part] = ss;
    }
    __syncthreads();
    if (t < 32){
        float s2 = 0.f;
        #pragma unroll
        for (int p=0; p<8; p++) s2 += ps[t][p];
        invn[t] = 1.f / fmaxf(sqrtf(s2), 1e-12f);
    }

    // bins: thread (hr, part) scans centroids [part*64, part*64+64) ascending
    float best = -3.4e38f; int bidx = 0;
    {
        const float* prow = &xs[row][head*HD];
        for (int jc=0; jc<64; jc++){
            int c = part*64 + jc;
            float acc = 0.f;
            if (!fc){
                const uint4* cp = (const uint4*)((const u16*)cen + (size_t)c*HD);
                #pragma unroll
                for (int p=0; p<8; p++){
                    uint4 u = cp[p];
                    fma8(prow + p*8, u.x, u.y, u.z, u.w, acc);
                }
            } else {
                const float4* cp = (const float4*)((const float*)cen + (size_t)c*HD);
                #pragma unroll
                for (int p=0; p<16; p++){
                    fma4f(prow + p*4, cp[p], acc);
                }
            }
            if (acc > best){ best = acc; bidx = c; }   // strict > keeps first max
        }
    }
    bvs[hr][part] = best; bis[hr][part] = bidx;
    __syncthreads();                       // also publishes invn

    if (t < 32){
        float bb2 = bvs[t][0]; int bi2 = bis[t][0];
        #pragma unroll
        for (int g=1; g<8; g++){           // ascending groups, strict > keeps lowest index
            float ov = bvs[t][g];
            if (ov > bb2){ bb2 = ov; bi2 = bis[t][g]; }
        }
        int token = r0 + (t>>3), hd2 = t&7;
        kbin[hd2*NTOK + token] = (u16)bi2;
    }

    // normalized bf16 store
    {
        int idx = t*8, row2 = idx>>9, col = idx&511, head2 = col>>6;
        float inv = invn[row2*8 + head2];
        const float* x = &xs[row2][col];
        uint4 v;
        v.x = pack2(x[0]*inv, x[1]*inv); v.y = pack2(x[2]*inv, x[3]*inv);
        v.z = pack2(x[4]*inv, x[5]*inv); v.w = pack2(x[6]*inv, x[7]*inv);
        ((uint4*)(OutB + (size_t)r0*EMBED))[t] = v;
    }
}

// ============ K2: attention; recomputes q-proj + q-norm + q-bin per block ============
// grid (2048, 8), block 256. Output (attention, pre-oproj) -> d_out in input dtype.
__global__ __launch_bounds__(256) void attn_kernel(
    const void* __restrict__ Xq, const void* __restrict__ Wq, const void* __restrict__ bq,
    const void* __restrict__ cen,
    const u16* __restrict__ Kb, const u16* __restrict__ Vb, const u16* __restrict__ kbin,
    void* __restrict__ out, const u32* __restrict__ flags)
{
    int q = blockIdx.x, h = blockIdx.y;
    int t = threadIdx.x;
    const u32 fx = flags[0], fw = flags[3], fb = flags[4], fc = flags[11];

    __shared__ float xq[512];
    __shared__ float part[4][64];
    __shared__ float qraw[64];
    __shared__ float qs[64];
    __shared__ float bcv[256];
    __shared__ int   bci[256];
    __shared__ int   s_myqb;
    __shared__ int cnt[256];
    __shared__ int sel[256];
    __shared__ float sc[256];
    __shared__ float red[256];

    // (a) stage query token row (512 elems)
    if (!fx){
        u32 u = ((const u32*)Xq)[q*256 + t];
        xq[2*t] = lof(u); xq[2*t+1] = hif(u);
    } else {
        float2 f = ((const float2*)Xq)[(size_t)q*256 + t];
        xq[2*t] = f.x; xq[2*t+1] = f.y;
    }
    __syncthreads();

    // (b) q-projection partials: d = t&63, p = t>>6 covers i in [p*128, p*128+128)
    {
        int d = t & 63, p = t >> 6;
        int row = h*HD + d;
        float acc = 0.f;
        if (!fw){
            const uint4* wr = (const uint4*)((const u16*)Wq + (size_t)row*EMBED + p*128);
            const float* x = xq + p*128;
            for (int i8=0; i8<16; i8++){
                uint4 u = wr[i8];
                fma8(x + i8*8, u.x, u.y, u.z, u.w, acc);
            }
        } else {
            const float4* wr = (const float4*)((const float*)Wq + (size_t)row*EMBED + p*128);
            const float* x = xq + p*128;
            for (int i4=0; i4<32; i4++){
                fma4f(x + i4*4, wr[i4], acc);
            }
        }
        part[p][d] = acc;
    }
    __syncthreads();
    if (t < 64){
        float b = fb ? ((const float*)bq)[h*HD+t] : bf2f(((const u16*)bq)[h*HD+t]);
        qraw[t] = part[0][t] + part[1][t] + part[2][t] + part[3][t] + b;
    }
    __syncthreads();
    if (t < 64){
        float ss = 0.f;
        #pragma unroll
        for (int d=0; d<64; d++) ss += qraw[d]*qraw[d];
        float inv = 1.f / fmaxf(sqrtf(ss), 1e-12f);
        qs[t] = qraw[t] * inv;             // consumed after later barriers
    }

    // (c) q-bin: thread t evaluates centroids {t, t+256} (ascending -> first-max kept)
    {
        float bestv = -3.4e38f; int besti = 0;
        #pragma unroll
        for (int cc=0; cc<2; cc++){
            int c = t + cc*256;
            float acc = 0.f;
            if (!fc){
                const uint4* cp = (const uint4*)((const u16*)cen + (size_t)c*HD);
                #pragma unroll
                for (int p2=0; p2<8; p2++){
                    uint4 u = cp[p2];
                    fma8(qraw + p2*8, u.x, u.y, u.z, u.w, acc);
                }
            } else {
                const float4* cp = (const float4*)((const float*)cen + (size_t)c*HD);
                #pragma unroll
                for (int p2=0; p2<16; p2++){
                    fma4f(qraw + p2*4, cp[p2], acc);
                }
            }
            if (acc > bestv){ bestv = acc; besti = c; }
        }
        bcv[t] = bestv; bci[t] = besti;
    }
    __syncthreads();
    for (int off=128; off; off>>=1){
        if (t < off){
            float v2 = bcv[t+off]; int i2 = bci[t+off];
            if (v2 > bcv[t] || (v2 == bcv[t] && i2 < bci[t])){ bcv[t] = v2; bci[t] = i2; }
        }
        __syncthreads();
    }
    if (t == 0) s_myqb = bci[0];
    __syncthreads();
    int myqb = s_myqb;

    // (d) neighbor mask over key bins; index-ordered truncation to MAXSEL
    uint4 kw = ((const uint4*)(kbin + h*NTOK))[t];
    int kk[8] = { (int)(kw.x & 0xffff), (int)(kw.x >> 16),
                  (int)(kw.y & 0xffff), (int)(kw.y >> 16),
                  (int)(kw.z & 0xffff), (int)(kw.z >> 16),
                  (int)(kw.w & 0xffff), (int)(kw.w >> 16) };
    int fl = 0, c = 0;
    #pragma unroll
    for (int j=0; j<8; j++){
        int d = (myqb - kk[j]) & (NBINS-1);
        int f = (d <= 1 || d >= NBINS-1) ? 1 : 0;
        fl |= f << j; c += f;
    }
    cnt[t] = c;
    __syncthreads();
    for (int off=1; off<256; off<<=1){
        int y = (t >= off) ? cnt[t-off] : 0;
        __syncthreads();
        cnt[t] += y;
        __syncthreads();
    }
    int total = cnt[255];
    int r = cnt[t] - c;                    // exclusive prefix
    int base = t*8;
    #pragma unroll
    for (int j=0; j<8; j++){
        if ((fl>>j)&1){
            r++;
            if (r <= MAXSEL) sel[r-1] = base + j;
        }
    }
    __syncthreads();
    if (total == 0) sel[t] = t;            // fallback: first 256 keys
    __syncthreads();
    int L = (total == 0) ? MAXSEL : min(total, MAXSEL);

    // (e) scores
    float s = -1e30f;
    if (t < L){
        const uint4* kr4 = (const uint4*)(Kb + (size_t)sel[t]*EMBED + h*HD);
        float acc = 0.f;
        #pragma unroll
        for (int p=0; p<8; p++){
            uint4 u = kr4[p];
            fma8(qs + p*8, u.x, u.y, u.z, u.w, acc);
        }
        s = acc * 0.125f;                  // 1/sqrt(64)
    }
    red[t] = s;
    __syncthreads();
    for (int off=128; off; off>>=1){
        if (t < off) red[t] = fmaxf(red[t], red[t+off]);
        __syncthreads();
    }
    float m = red[0];
    __syncthreads();
    float e = (t < L) ? __expf(fminf(s - m, 0.f)) : 0.f;
    sc[t] = e;
    red[t] = e;
    __syncthreads();
    for (int off=128; off; off>>=1){
        if (t < off) red[t] += red[t+off];
        __syncthreads();
    }
    float inv = 1.f / fmaxf(red[0], 1e-37f);
    if (t < 64){
        float acc = 0.f;
        for (int j=0; j<L; j++){
            acc += sc[j] * bf2f(Vb[(size_t)sel[j]*EMBED + h*HD + t]);
        }
        float o = acc * inv;
        if (!fx) ((u16*)out)[(size_t)q*EMBED + h*HD + t] = f2b(o);
        else     ((float*)out)[(size_t)q*EMBED + h*HD + t] = o;
    }
}

// ============ K3: output projection, in place on d_out ============
// grid (512), block 256. Stages its 4 rows into LDS BEFORE overwriting them.
// Same-dtype in-place (element byte spans identical) -> no cross-block races.
__global__ __launch_bounds__(256) void oproj_kernel(
    void* out, const void* __restrict__ Wo, const void* __restrict__ bo,
    const u32* __restrict__ flags)
{
    const u32 fx = flags[0], fw = flags[9], fb = flags[10];
    int r0 = blockIdx.x * 4;
    int t = threadIdx.x;
    __shared__ float xs[4][512];
    if (!fx){
        uint4 u = ((const uint4*)((const u16*)out + (size_t)r0*EMBED))[t];
        float* xr = &xs[0][0] + t*8;
        xr[0]=lof(u.x); xr[1]=hif(u.x); xr[2]=lof(u.y); xr[3]=hif(u.y);
        xr[4]=lof(u.z); xr[5]=hif(u.z); xr[6]=lof(u.w); xr[7]=hif(u.w);
    } else {
        const float4* A4 = (const float4*)((const float*)out + (size_t)r0*EMBED);
        float4 f = A4[t];
        float* xr = &xs[0][0] + t*4;
        xr[0]=f.x; xr[1]=f.y; xr[2]=f.z; xr[3]=f.w;
        f = A4[t+256];
        xr = &xs[0][0] + (t+256)*4;
        xr[0]=f.x; xr[1]=f.y; xr[2]=f.z; xr[3]=f.w;
    }
    __syncthreads();
    float a0[4] = {0.f,0.f,0.f,0.f};
    float a1[4] = {0.f,0.f,0.f,0.f};
    if (!fw){
        const uint4* wr0 = (const uint4*)((const u16*)Wo + (size_t)t*EMBED);
        const uint4* wr1 = (const uint4*)((const u16*)Wo + (size_t)(t+256)*EMBED);
        for (int i8=0; i8<64; i8++){
            uint4 w0 = wr0[i8];
            uint4 w1 = wr1[i8];
            #pragma unroll
            for (int r=0; r<4; r++){
                const float* x = &xs[r][i8*8];
                fma8(x, w0.x, w0.y, w0.z, w0.w, a0[r]);
                fma8(x, w1.x, w1.y, w1.z, w1.w, a1[r]);
            }
        }
    } else {
        const float4* wr0 = (const float4*)((const float*)Wo + (size_t)t*EMBED);
        const float4* wr1 = (const float4*)((const float*)Wo + (size_t)(t+256)*EMBED);
        for (int i4=0; i4<128; i4++){
            float4 w0 = wr0[i4];
            float4 w1 = wr1[i4];
            #pragma unroll
            for (int r=0; r<4; r++){
                const float* x = &xs[r][i4*4];
                fma4f(x, w0, a0[r]);
                fma4f(x, w1, a1[r]);
            }
        }
    }
    float b0 = fb ? ((const float*)bo)[t]     : bf2f(((const u16*)bo)[t]);
    float b1 = fb ? ((const float*)bo)[t+256] : bf2f(((const u16*)bo)[t+256]);
    if (!fx){
        u16* o = (u16*)out;
        #pragma unroll
        for (int r=0; r<4; r++){
            o[(size_t)(r0+r)*EMBED + t]       = f2b(a0[r]+b0);
            o[(size_t)(r0+r)*EMBED + t + 256] = f2b(a1[r]+b1);
        }
    } else {
        float* o = (float*)out;
        #pragma unroll
        for (int r=0; r<4; r++){
            o[(size_t)(r0+r)*EMBED + t]       = a0[r]+b0;
            o[(size_t)(r0+r)*EMBED + t + 256] = a1[r]+b1;
        }
    }
}

extern "C" void kernel_launch(void* const* d_in, const int* in_sizes, int n_in,
                              void* d_out, int out_size, void* d_ws, size_t ws_size,
                              hipStream_t stream)
{
    const void* query = d_in[0];
    const void* key   = d_in[1];
    const void* value = d_in[2];
    const void* Wq = d_in[3];
    const void* bq = d_in[4];
    const void* Wk = d_in[5];
    const void* bk = d_in[6];
    const void* Wv = d_in[7];
    const void* bv = d_in[8];
    const void* Wo = d_in[9];
    const void* bo = d_in[10];
    const void* cen = d_in[11];

    // ws layout (4.06 MB total):
    //   [0, 64)           flags u32[16]
    //   [4096, 36864)     kbin u16[16384]
    //   [64K, 64K+2M)     Kb bf16 (normalized)
    //   [64K+2M, 64K+4M)  Vb bf16 (raw)
    char* ws = (char*)d_ws;
    u32* flags = (u32*)ws;
    u16* kbin  = (u16*)(ws + 4096);
    u16* Kb    = (u16*)(ws + (size_t)64*1024);
    u16* Vb    = (u16*)(ws + (size_t)64*1024 + (size_t)2*1024*1024);

    sniff_kernel<<<12, 64, 0, stream>>>(query,key,value,Wq,bq,Wk,bk,Wv,bv,Wo,bo,cen, flags);
    projkv_kernel<<<dim3(512,2), 256, 0, stream>>>(key,value,Wk,bk,Wv,bv,cen,flags,Kb,Vb,kbin);
    attn_kernel<<<dim3(2048,8), 256, 0, stream>>>(query,Wq,bq,cen,Kb,Vb,kbin,d_out,flags);
    oproj_kernel<<<512, 256, 0, stream>>>(d_out,Wo,bo,flags);
}

// Round 8
// 736.829 us; speedup vs baseline: 1.3100x; 1.3100x over previous
//
#include <hip/hip_runtime.h>
#include <hip/hip_bf16.h>

#define NTOK 2048
#define EMBED 512
#define NHEADS 8
#define HD 64
#define NBINS 512
#define MAXSEL 256

typedef unsigned short u16;
typedef unsigned int u32;
typedef short s16x8 __attribute__((ext_vector_type(8)));
typedef float f32x4 __attribute__((ext_vector_type(4)));

__device__ __forceinline__ float lof(u32 u){ return __uint_as_float(u << 16); }
__device__ __forceinline__ float hif(u32 u){ return __uint_as_float(u & 0xffff0000u); }
__device__ __forceinline__ float bf2f(u16 u){ return __uint_as_float(((u32)u) << 16); }
__device__ __forceinline__ u16 f2b(float f){
    __hip_bfloat16 h = __float2bfloat16(f);
    return *(u16*)&h;
}
__device__ __forceinline__ u32 pack2(float lo, float hi){
    return (u32)f2b(lo) | ((u32)f2b(hi) << 16);
}
__device__ __forceinline__ void fma8(const float* x, u32 ux, u32 uy, u32 uz, u32 uw, float& a){
    a += x[0]*lof(ux) + x[1]*hif(ux) + x[2]*lof(uy) + x[3]*hif(uy)
       + x[4]*lof(uz) + x[5]*hif(uz) + x[6]*lof(uw) + x[7]*hif(uw);
}
__device__ __forceinline__ void fma4f(const float* x, float4 w, float& a){
    a += x[0]*w.x + x[1]*w.y + x[2]*w.z + x[3]*w.w;
}

// Inline per-block dtype sniff: read 64 even u16s of the tensor as bf16.
// f32 data -> low mantissa halves -> random bf16 exponents -> max>100 w.p. 1-6e-19.
// bf16 data here (|x|<6) -> max<10. All threads same samples -> uniform, no comm.
__device__ __forceinline__ u32 sniffp(const void* p){
    const u16* s = (const u16*)p;
    float m = 0.f;
    #pragma unroll
    for (int k=0; k<64; k++) m = fmaxf(m, fabsf(bf2f(s[2*k])));
    return (m > 100.f) ? 1u : 0u;
}

// ============ K1: QKV projection (MFMA) + per-head norm + centroid bins ============
// grid (128, 3): 16 tokens/block, y: 0=Q 1=K 2=V. block 256 (4 waves, 2 heads/wave).
__global__ __launch_bounds__(256) void projqkv_kernel(
    const void* __restrict__ Xq, const void* __restrict__ Xk, const void* __restrict__ Xv,
    const void* __restrict__ Wq, const void* __restrict__ bq,
    const void* __restrict__ Wk, const void* __restrict__ bk,
    const void* __restrict__ Wv, const void* __restrict__ bv,
    const void* __restrict__ cen,
    void* __restrict__ outQ,                 // d_out: normalized Q staging (query dtype)
    u16* __restrict__ Kb, u16* __restrict__ Vb,
    u16* __restrict__ qbin, u16* __restrict__ kbin)
{
    int which = blockIdx.y;
    const void *X, *W, *Bb;
    if (which==0){ X=Xq; W=Wq; Bb=bq; }
    else if (which==1){ X=Xk; W=Wk; Bb=bk; }
    else { X=Xv; W=Wv; Bb=bv; }
    u32 fx = sniffp(X), fw = sniffp(W), fb = sniffp(Bb);
    int r0 = blockIdx.x * 16;
    int t = threadIdx.x;

    __shared__ u16  xsb[16*520];     // bf16 X tile, padded rows (MFMA path)
    __shared__ float xf[4][512];     // f32 staging (fallback path)
    __shared__ float ps[128*65];     // projections f32: [(tokrow*8+head)][65]
    __shared__ float nrm2[128][2];
    __shared__ float invn[128];
    __shared__ float bvl[128][2];
    __shared__ int   bil[128][2];

    if (!(fx|fw|fb)){
        // ---------- MFMA path (all-bf16) ----------
        {
            int row = t>>4, seg = t&15;
            const uint4* src = (const uint4*)((const u16*)X + (size_t)(r0+row)*EMBED + seg*32);
            uint4* dst = (uint4*)(xsb + row*520 + seg*32);
            dst[0] = src[0]; dst[1] = src[1];
        }
        __syncthreads();
        int lane = t&63, wave = t>>6;
        int m = lane&15, quad = lane>>4;
        int obase = wave*128;
        f32x4 acc[8];
        #pragma unroll
        for (int i=0;i<8;i++){ f32x4 z = {0.f,0.f,0.f,0.f}; acc[i] = z; }
        const u16* arow = xsb + m*520 + quad*8;
        const u16* wp = (const u16*)W;
        for (int k=0;k<16;k++){
            int i0 = k*32;
            s16x8 a = *(const s16x8*)(arow + i0);
            #pragma unroll
            for (int tile=0;tile<8;tile++){
                int o = obase + tile*16 + m;
                s16x8 b = *(const s16x8*)(wp + (size_t)o*EMBED + i0 + quad*8);
                acc[tile] = __builtin_amdgcn_mfma_f32_16x16x32_bf16(a, b, acc[tile], 0, 0, 0);
            }
        }
        #pragma unroll
        for (int tile=0;tile<8;tile++){
            int o = obase + tile*16 + m;
            float bias = bf2f(((const u16*)Bb)[o]);
            int head = o>>6, c = o&63;
            #pragma unroll
            for (int reg=0;reg<4;reg++){
                int row = quad*4 + reg;
                ps[(row*8+head)*65 + c] = acc[tile][reg] + bias;
            }
        }
    } else {
        // ---------- f32/VALU fallback (4 rows per pass) ----------
        for (int g=0; g<4; g++){
            {
                float* xr = &xf[0][0] + t*8;
                if (!fx){
                    uint4 u = ((const uint4*)((const u16*)X + (size_t)(r0+g*4)*EMBED))[t];
                    xr[0]=lof(u.x); xr[1]=hif(u.x); xr[2]=lof(u.y); xr[3]=hif(u.y);
                    xr[4]=lof(u.z); xr[5]=hif(u.z); xr[6]=lof(u.w); xr[7]=hif(u.w);
                } else {
                    const float4* X4 = (const float4*)((const float*)X + (size_t)(r0+g*4)*EMBED);
                    float4 fa = X4[2*t], fb2 = X4[2*t+1];
                    xr[0]=fa.x; xr[1]=fa.y; xr[2]=fa.z; xr[3]=fa.w;
                    xr[4]=fb2.x; xr[5]=fb2.y; xr[6]=fb2.z; xr[7]=fb2.w;
                }
            }
            __syncthreads();
            float a0[4]={0.f,0.f,0.f,0.f}, a1[4]={0.f,0.f,0.f,0.f};
            if (!fw){
                const uint4* wr0 = (const uint4*)((const u16*)W + (size_t)t*EMBED);
                const uint4* wr1 = (const uint4*)((const u16*)W + (size_t)(t+256)*EMBED);
                for (int i8=0;i8<64;i8++){
                    uint4 w0 = wr0[i8], w1 = wr1[i8];
                    #pragma unroll
                    for (int r=0;r<4;r++){
                        const float* x = &xf[r][i8*8];
                        fma8(x, w0.x,w0.y,w0.z,w0.w, a0[r]);
                        fma8(x, w1.x,w1.y,w1.z,w1.w, a1[r]);
                    }
                }
            } else {
                const float4* wr0 = (const float4*)((const float*)W + (size_t)t*EMBED);
                const float4* wr1 = (const float4*)((const float*)W + (size_t)(t+256)*EMBED);
                for (int i4=0;i4<128;i4++){
                    float4 w0 = wr0[i4], w1 = wr1[i4];
                    #pragma unroll
                    for (int r=0;r<4;r++){
                        const float* x = &xf[r][i4*4];
                        fma4f(x, w0, a0[r]);
                        fma4f(x, w1, a1[r]);
                    }
                }
            }
            float b0 = fb ? ((const float*)Bb)[t]     : bf2f(((const u16*)Bb)[t]);
            float b1 = fb ? ((const float*)Bb)[t+256] : bf2f(((const u16*)Bb)[t+256]);
            #pragma unroll
            for (int r=0;r<4;r++){
                int row = g*4+r;
                int c0 = t, c1 = t+256;
                ps[(row*8+(c0>>6))*65 + (c0&63)] = a0[r]+b0;
                ps[(row*8+(c1>>6))*65 + (c1&63)] = a1[r]+b1;
            }
            __syncthreads();
        }
    }
    __syncthreads();

    int hr = t>>1, half = t&1;                  // head-row 0..127, column half
    if (which == 2){
        // V: store raw bf16 (32 elems per thread)
        int row = hr>>3, head = hr&7;
        const float* src = ps + hr*65 + half*32;
        u16* dst = Vb + (size_t)(r0+row)*EMBED + head*64 + half*32;
        #pragma unroll
        for (int j8=0;j8<4;j8++){
            uint4 v;
            v.x = pack2(src[j8*8+0],src[j8*8+1]); v.y = pack2(src[j8*8+2],src[j8*8+3]);
            v.z = pack2(src[j8*8+4],src[j8*8+5]); v.w = pack2(src[j8*8+6],src[j8*8+7]);
            ((uint4*)dst)[j8] = v;
        }
        return;
    }

    u32 fc = sniffp(cen);
    // per-head sumsq partials
    {
        const float* src = ps + hr*65 + half*32;
        float ss = 0.f;
        #pragma unroll
        for (int d=0;d<32;d++) ss += src[d]*src[d];
        nrm2[hr][half] = ss;
    }
    // bins from f32 projections: thread (hr, half) scans centroids [half*256, +256) ascending
    float xv[64];
    {
        const float* src = ps + hr*65;
        #pragma unroll
        for (int d=0;d<64;d++) xv[d] = src[d];
    }
    float best = -3.4e38f; int bidx = 0;
    for (int jc=0;jc<256;jc++){
        int c = half*256 + jc;
        float acc = 0.f;
        if (!fc){
            const uint4* cp = (const uint4*)((const u16*)cen + (size_t)c*HD);
            #pragma unroll
            for (int p=0;p<8;p++){ uint4 u = cp[p]; fma8(xv+p*8, u.x,u.y,u.z,u.w, acc); }
        } else {
            const float4* cp = (const float4*)((const float*)cen + (size_t)c*HD);
            #pragma unroll
            for (int p=0;p<16;p++) fma4f(xv+p*4, cp[p], acc);
        }
        if (acc > best){ best = acc; bidx = c; }    // strict > keeps first max
    }
    bvl[hr][half] = best; bil[hr][half] = bidx;
    __syncthreads();
    if (half == 0){
        invn[hr] = 1.f / fmaxf(sqrtf(nrm2[hr][0]+nrm2[hr][1]), 1e-12f);
        float v0 = bvl[hr][0]; int i0b = bil[hr][0];
        float v1 = bvl[hr][1]; int i1b = bil[hr][1];
        if (v1 > v0 || (v1 == v0 && i1b < i0b)){ v0 = v1; i0b = i1b; }
        u16* bins = (which==0) ? qbin : kbin;
        int token = r0 + (hr>>3), head = hr&7;
        bins[head*NTOK + token] = (u16)i0b;
    }
    __syncthreads();
    // normalized store: Q -> outQ (query dtype), K -> Kb (bf16)
    {
        float inv = invn[hr];
        const float* src = ps + hr*65 + half*32;
        int row = hr>>3, head = hr&7;
        size_t off = (size_t)(r0+row)*EMBED + head*64 + half*32;
        if (which == 1){
            u16* dst = Kb + off;
            #pragma unroll
            for (int j8=0;j8<4;j8++){
                uint4 v;
                v.x = pack2(src[j8*8+0]*inv, src[j8*8+1]*inv);
                v.y = pack2(src[j8*8+2]*inv, src[j8*8+3]*inv);
                v.z = pack2(src[j8*8+4]*inv, src[j8*8+5]*inv);
                v.w = pack2(src[j8*8+6]*inv, src[j8*8+7]*inv);
                ((uint4*)dst)[j8] = v;
            }
        } else if (!fx){
            u16* dst = (u16*)outQ + off;
            #pragma unroll
            for (int j8=0;j8<4;j8++){
                uint4 v;
                v.x = pack2(src[j8*8+0]*inv, src[j8*8+1]*inv);
                v.y = pack2(src[j8*8+2]*inv, src[j8*8+3]*inv);
                v.z = pack2(src[j8*8+4]*inv, src[j8*8+5]*inv);
                v.w = pack2(src[j8*8+6]*inv, src[j8*8+7]*inv);
                ((uint4*)dst)[j8] = v;
            }
        } else {
            float* dst = (float*)outQ + off;
            #pragma unroll
            for (int j=0;j<32;j++) dst[j] = src[j]*inv;
        }
    }
}

// ============ K2: attention ============
// grid 2048 (one block per query token), 4 waves x 2 heads. Qb read from d_out row q,
// AO written back to the same row (race-free). Wave-level scan, minimal barriers.
__global__ __launch_bounds__(256) void attn_kernel(
    const void* __restrict__ query,
    const u16* __restrict__ Kb, const u16* __restrict__ Vb,
    const u16* __restrict__ qbin, const u16* __restrict__ kbin,
    void* __restrict__ out)
{
    u32 fq = sniffp(query);
    int q = blockIdx.x, t = threadIdx.x;
    int wave = t>>6, lane = t&63;
    __shared__ float qs[512];
    __shared__ float sc[4][256];
    __shared__ u16   sel[4][256];

    if (!fq){
        u32 u = ((const u32*)out)[(size_t)q*256 + t];
        qs[2*t] = lof(u); qs[2*t+1] = hif(u);
    } else {
        float2 f = ((const float2*)out)[(size_t)q*256 + t];
        qs[2*t] = f.x; qs[2*t+1] = f.y;
    }
    __syncthreads();

    for (int hh=0; hh<2; hh++){
        int h = wave*2 + hh;
        int myqb = qbin[h*NTOK + q];
        // mask over this lane's 32 keys
        const uint4* kbp = (const uint4*)(kbin + h*NTOK + lane*32);
        u32 fl = 0;
        #pragma unroll
        for (int w4=0; w4<4; w4++){
            uint4 kw = kbp[w4];
            u32 arr[4] = {kw.x, kw.y, kw.z, kw.w};
            #pragma unroll
            for (int e=0;e<4;e++){
                int b0 = (int)(arr[e] & 0xffff), b1 = (int)(arr[e] >> 16);
                int d0 = (myqb - b0) & (NBINS-1), d1 = (myqb - b1) & (NBINS-1);
                if (d0 <= 1 || d0 >= NBINS-1) fl |= 1u << (w4*8 + e*2);
                if (d1 <= 1 || d1 >= NBINS-1) fl |= 1u << (w4*8 + e*2 + 1);
            }
        }
        int cnt = __popc(fl);
        int sum = cnt;
        #pragma unroll
        for (int off=1; off<64; off<<=1){
            int v = __shfl_up(sum, off, 64);
            if (lane >= off) sum += v;
        }
        int total = __shfl(sum, 63, 64);
        int r = sum - cnt;                       // exclusive prefix
        if (total){
            u32 f2 = fl;
            while (f2){
                int j = __ffs(f2) - 1; f2 &= f2 - 1;   // ascending j -> index order
                if (r < MAXSEL) sel[wave][r] = (u16)(lane*32 + j);
                r++;
            }
        } else {
            #pragma unroll
            for (int kq=0;kq<4;kq++) sel[wave][lane*4+kq] = (u16)(lane*4+kq);
        }
        int L = total ? min(total, MAXSEL) : MAXSEL;
        __syncthreads();
        // scores
        const float* qh = qs + h*64;
        float mloc = -3.4e38f;
        for (int jj=lane; jj<L; jj+=64){
            int kkey = sel[wave][jj];
            const uint4* kr = (const uint4*)(Kb + (size_t)kkey*EMBED + h*64);
            float acc = 0.f;
            #pragma unroll
            for (int p=0;p<8;p++){ uint4 u = kr[p]; fma8(qh+p*8, u.x,u.y,u.z,u.w, acc); }
            float s = acc * 0.125f;
            sc[wave][jj] = s;
            mloc = fmaxf(mloc, s);
        }
        #pragma unroll
        for (int off=32; off; off>>=1) mloc = fmaxf(mloc, __shfl_xor(mloc, off, 64));
        float ssum = 0.f;
        for (int jj=lane; jj<L; jj+=64){
            float e = __expf(sc[wave][jj] - mloc);
            sc[wave][jj] = e; ssum += e;
        }
        #pragma unroll
        for (int off=32; off; off>>=1) ssum += __shfl_xor(ssum, off, 64);
        float inv = 1.f / fmaxf(ssum, 1e-37f);
        __syncthreads();
        // PV: lane = output dim
        float acc = 0.f;
        for (int j=0; j<L; j++){
            int kkey = sel[wave][j];
            acc += sc[wave][j] * bf2f(Vb[(size_t)kkey*EMBED + h*64 + lane]);
        }
        float o = acc * inv;
        if (!fq) ((u16*)out)[(size_t)q*EMBED + h*64 + lane] = f2b(o);
        else     ((float*)out)[(size_t)q*EMBED + h*64 + lane] = o;
        __syncthreads();
    }
}

// ============ K3: output projection (MFMA), in place on d_out ============
// grid 128: 16 rows/block, staged fully before overwrite.
__global__ __launch_bounds__(256) void oproj_kernel(
    void* __restrict__ out, const void* __restrict__ Wo, const void* __restrict__ bo)
{
    u32 fq = sniffp(out);                 // AO dtype (== query dtype from K2)
    u32 fw = sniffp(Wo), fb = sniffp(bo);
    int r0 = blockIdx.x * 16;
    int t = threadIdx.x;
    __shared__ u16  ab[16*520];
    __shared__ float xf[4][512];

    if (!(fq|fw|fb)){
        {
            int row = t>>4, seg = t&15;
            const uint4* src = (const uint4*)((const u16*)out + (size_t)(r0+row)*EMBED + seg*32);
            uint4* dst = (uint4*)(ab + row*520 + seg*32);
            dst[0] = src[0]; dst[1] = src[1];
        }
        __syncthreads();
        int lane = t&63, wave = t>>6;
        int m = lane&15, quad = lane>>4;
        int obase = wave*128;
        f32x4 acc[8];
        #pragma unroll
        for (int i=0;i<8;i++){ f32x4 z = {0.f,0.f,0.f,0.f}; acc[i] = z; }
        const u16* arow = ab + m*520 + quad*8;
        const u16* wp = (const u16*)Wo;
        for (int k=0;k<16;k++){
            int i0 = k*32;
            s16x8 a = *(const s16x8*)(arow + i0);
            #pragma unroll
            for (int tile=0;tile<8;tile++){
                int o = obase + tile*16 + m;
                s16x8 b = *(const s16x8*)(wp + (size_t)o*EMBED + i0 + quad*8);
                acc[tile] = __builtin_amdgcn_mfma_f32_16x16x32_bf16(a, b, acc[tile], 0, 0, 0);
            }
        }
        #pragma unroll
        for (int tile=0;tile<8;tile++){
            int o = obase + tile*16 + m;
            float bias = bf2f(((const u16*)bo)[o]);
            #pragma unroll
            for (int reg=0;reg<4;reg++){
                int row = quad*4 + reg;
                ((u16*)out)[(size_t)(r0+row)*EMBED + o] = f2b(acc[tile][reg] + bias);
            }
        }
    } else {
        for (int g=0; g<4; g++){
            {
                float* xr = &xf[0][0] + t*8;
                if (!fq){
                    uint4 u = ((const uint4*)((const u16*)out + (size_t)(r0+g*4)*EMBED))[t];
                    xr[0]=lof(u.x); xr[1]=hif(u.x); xr[2]=lof(u.y); xr[3]=hif(u.y);
                    xr[4]=lof(u.z); xr[5]=hif(u.z); xr[6]=lof(u.w); xr[7]=hif(u.w);
                } else {
                    const float4* A4 = (const float4*)((const float*)out + (size_t)(r0+g*4)*EMBED);
                    float4 fa = A4[2*t], fb2 = A4[2*t+1];
                    xr[0]=fa.x; xr[1]=fa.y; xr[2]=fa.z; xr[3]=fa.w;
                    xr[4]=fb2.x; xr[5]=fb2.y; xr[6]=fb2.z; xr[7]=fb2.w;
                }
            }
            __syncthreads();
            float a0[4]={0.f,0.f,0.f,0.f}, a1[4]={0.f,0.f,0.f,0.f};
            if (!fw){
                const uint4* wr0 = (const uint4*)((const u16*)Wo + (size_t)t*EMBED);
                const uint4* wr1 = (const uint4*)((const u16*)Wo + (size_t)(t+256)*EMBED);
                for (int i8=0;i8<64;i8++){
                    uint4 w0 = wr0[i8], w1 = wr1[i8];
                    #pragma unroll
                    for (int r=0;r<4;r++){
                        const float* x = &xf[r][i8*8];
                        fma8(x, w0.x,w0.y,w0.z,w0.w, a0[r]);
                        fma8(x, w1.x,w1.y,w1.z,w1.w, a1[r]);
                    }
                }
            } else {
                const float4* wr0 = (const float4*)((const float*)Wo + (size_t)t*EMBED);
                const float4* wr1 = (const float4*)((const float*)Wo + (size_t)(t+256)*EMBED);
                for (int i4=0;i4<128;i4++){
                    float4 w0 = wr0[i4], w1 = wr1[i4];
                    #pragma unroll
                    for (int r=0;r<4;r++){
                        const float* x = &xf[r][i4*4];
                        fma4f(x, w0, a0[r]);
                        fma4f(x, w1, a1[r]);
                    }
                }
            }
            float b0 = fb ? ((const float*)bo)[t]     : bf2f(((const u16*)bo)[t]);
            float b1 = fb ? ((const float*)bo)[t+256] : bf2f(((const u16*)bo)[t+256]);
            if (!fq){
                u16* o = (u16*)out;
                #pragma unroll
                for (int r=0;r<4;r++){
                    o[(size_t)(r0+g*4+r)*EMBED + t]       = f2b(a0[r]+b0);
                    o[(size_t)(r0+g*4+r)*EMBED + t + 256] = f2b(a1[r]+b1);
                }
            } else {
                float* o = (float*)out;
                #pragma unroll
                for (int r=0;r<4;r++){
                    o[(size_t)(r0+g*4+r)*EMBED + t]       = a0[r]+b0;
                    o[(size_t)(r0+g*4+r)*EMBED + t + 256] = a1[r]+b1;
                }
            }
            __syncthreads();
        }
    }
}

extern "C" void kernel_launch(void* const* d_in, const int* in_sizes, int n_in,
                              void* d_out, int out_size, void* d_ws, size_t ws_size,
                              hipStream_t stream)
{
    const void* query = d_in[0];
    const void* key   = d_in[1];
    const void* value = d_in[2];
    const void* Wq = d_in[3];
    const void* bq = d_in[4];
    const void* Wk = d_in[5];
    const void* bk = d_in[6];
    const void* Wv = d_in[7];
    const void* bv = d_in[8];
    const void* Wo = d_in[9];
    const void* bo = d_in[10];
    const void* cen = d_in[11];

    // ws layout (4,259,840 B total — exactly the round-7-proven footprint):
    //   [0, 32K)        qbin u16[16384]
    //   [32K, 64K)      kbin u16[16384]
    //   [64K, 64K+2M)   Kb bf16 (normalized)
    //   [64K+2M, +2M)   Vb bf16 (raw)
    char* ws = (char*)d_ws;
    u16* qbin = (u16*)ws;
    u16* kbin = (u16*)(ws + 32768);
    u16* Kb   = (u16*)(ws + 65536);
    u16* Vb   = (u16*)(ws + 65536 + (size_t)2*1024*1024);

    projqkv_kernel<<<dim3(128,3), 256, 0, stream>>>(query,key,value,Wq,bq,Wk,bk,Wv,bv,cen,
                                                    d_out,Kb,Vb,qbin,kbin);
    attn_kernel<<<2048, 256, 0, stream>>>(query,Kb,Vb,qbin,kbin,d_out);
    oproj_kernel<<<128, 256, 0, stream>>>(d_out,Wo,bo);
}

// Round 9
// 540.518 us; speedup vs baseline: 1.7857x; 1.3632x over previous
//
#include <hip/hip_runtime.h>
#include <hip/hip_bf16.h>

#define NTOK 2048
#define EMBED 512
#define NHEADS 8
#define HD 64
#define NBINS 512
#define MAXSEL 256

typedef unsigned short u16;
typedef unsigned int u32;
typedef short s16x8 __attribute__((ext_vector_type(8)));
typedef float f32x4 __attribute__((ext_vector_type(4)));

__device__ __forceinline__ float lof(u32 u){ return __uint_as_float(u << 16); }
__device__ __forceinline__ float hif(u32 u){ return __uint_as_float(u & 0xffff0000u); }
__device__ __forceinline__ float bf2f(u16 u){ return __uint_as_float(((u32)u) << 16); }
__device__ __forceinline__ u16 f2b(float f){
    __hip_bfloat16 h = __float2bfloat16(f);
    return *(u16*)&h;
}
__device__ __forceinline__ u32 pack2(float lo, float hi){
    return (u32)f2b(lo) | ((u32)f2b(hi) << 16);
}
__device__ __forceinline__ void fma8(const float* x, u32 ux, u32 uy, u32 uz, u32 uw, float& a){
    a += x[0]*lof(ux) + x[1]*hif(ux) + x[2]*lof(uy) + x[3]*hif(uy)
       + x[4]*lof(uz) + x[5]*hif(uz) + x[6]*lof(uw) + x[7]*hif(uw);
}
__device__ __forceinline__ void fma4f(const float* x, float4 w, float& a){
    a += x[0]*w.x + x[1]*w.y + x[2]*w.z + x[3]*w.w;
}

// Inline per-block dtype sniff: read 64 even u16s of the tensor as bf16.
// f32 data -> low mantissa halves -> random bf16 exponents -> max>100 w.p. ~1.
// bf16 data here (|x|<6) -> max<10. All threads same samples -> uniform branch.
__device__ __forceinline__ u32 sniffp(const void* p){
    const u16* s = (const u16*)p;
    float m = 0.f;
    #pragma unroll
    for (int k=0; k<64; k++) m = fmaxf(m, fabsf(bf2f(s[2*k])));
    return (m > 100.f) ? 1u : 0u;
}

// ============ K1: QKV projection + per-head norm + centroid bins (LDS-GEMM scan) ============
// grid (128, 3): 16 tokens/block, y: 0=Q 1=K 2=V. block 256.
__global__ __launch_bounds__(256) void projqkv_kernel(
    const void* __restrict__ Xq, const void* __restrict__ Xk, const void* __restrict__ Xv,
    const void* __restrict__ Wq, const void* __restrict__ bq,
    const void* __restrict__ Wk, const void* __restrict__ bk,
    const void* __restrict__ Wv, const void* __restrict__ bv,
    const void* __restrict__ cen,
    void* __restrict__ outQ,                 // d_out: normalized Q staging (query dtype)
    u16* __restrict__ Kb, u16* __restrict__ Vb,
    u16* __restrict__ qbin, u16* __restrict__ kbin)
{
    int which = blockIdx.y;
    const void *X, *W, *Bb;
    if (which==0){ X=Xq; W=Wq; Bb=bq; }
    else if (which==1){ X=Xk; W=Wk; Bb=bk; }
    else { X=Xv; W=Wv; Bb=bv; }
    u32 fx = sniffp(X), fw = sniffp(W), fb = sniffp(Bb);
    int r0 = blockIdx.x * 16;
    int t = threadIdx.x;

    // ubuf phases: [GEMM] xsb 16x520 u16 (16640 B) or xf 4x512 f32 (8192 B)
    //              [scan] centT 64x68 f32 (17408 B)  -- max 17408
    __shared__ __align__(16) char ubuf[17408];
    __shared__ float ps[128*65];         // f32 projections [(tokrow*8+head)][65]
    __shared__ float nrm2[128][2];
    __shared__ float invn[128];
    __shared__ float bvl[128][8];
    __shared__ int   bil[128][8];

    if (!(fx|fw|fb)){
        // ---------- MFMA path (all-bf16) ----------
        u16* xsb = (u16*)ubuf;
        {
            int row = t>>4, seg = t&15;
            const uint4* src = (const uint4*)((const u16*)X + (size_t)(r0+row)*EMBED + seg*32);
            uint4* dst = (uint4*)(xsb + row*520 + seg*32);
            dst[0] = src[0]; dst[1] = src[1];
        }
        __syncthreads();
        int lane = t&63, wave = t>>6;
        int m = lane&15, quad = lane>>4;
        int obase = wave*128;
        f32x4 acc[8];
        #pragma unroll
        for (int i=0;i<8;i++){ f32x4 z = {0.f,0.f,0.f,0.f}; acc[i] = z; }
        const u16* arow = xsb + m*520 + quad*8;
        const u16* wp = (const u16*)W;
        for (int k=0;k<16;k++){
            int i0 = k*32;
            s16x8 a = *(const s16x8*)(arow + i0);
            #pragma unroll
            for (int tile=0;tile<8;tile++){
                int o = obase + tile*16 + m;
                s16x8 b = *(const s16x8*)(wp + (size_t)o*EMBED + i0 + quad*8);
                acc[tile] = __builtin_amdgcn_mfma_f32_16x16x32_bf16(a, b, acc[tile], 0, 0, 0);
            }
        }
        #pragma unroll
        for (int tile=0;tile<8;tile++){
            int o = obase + tile*16 + m;
            float bias = bf2f(((const u16*)Bb)[o]);
            int head = o>>6, c = o&63;
            #pragma unroll
            for (int reg=0;reg<4;reg++){
                int row = quad*4 + reg;
                ps[(row*8+head)*65 + c] = acc[tile][reg] + bias;
            }
        }
    } else {
        // ---------- f32/VALU fallback (4 rows per pass) ----------
        float* xf = (float*)ubuf;           // [4][512]
        for (int g=0; g<4; g++){
            {
                float* xr = xf + t*8;
                if (!fx){
                    uint4 u = ((const uint4*)((const u16*)X + (size_t)(r0+g*4)*EMBED))[t];
                    xr[0]=lof(u.x); xr[1]=hif(u.x); xr[2]=lof(u.y); xr[3]=hif(u.y);
                    xr[4]=lof(u.z); xr[5]=hif(u.z); xr[6]=lof(u.w); xr[7]=hif(u.w);
                } else {
                    const float4* X4 = (const float4*)((const float*)X + (size_t)(r0+g*4)*EMBED);
                    float4 fa = X4[2*t], fb2 = X4[2*t+1];
                    xr[0]=fa.x; xr[1]=fa.y; xr[2]=fa.z; xr[3]=fa.w;
                    xr[4]=fb2.x; xr[5]=fb2.y; xr[6]=fb2.z; xr[7]=fb2.w;
                }
            }
            __syncthreads();
            float a0[4]={0.f,0.f,0.f,0.f}, a1[4]={0.f,0.f,0.f,0.f};
            if (!fw){
                const uint4* wr0 = (const uint4*)((const u16*)W + (size_t)t*EMBED);
                const uint4* wr1 = (const uint4*)((const u16*)W + (size_t)(t+256)*EMBED);
                for (int i8=0;i8<64;i8++){
                    uint4 w0 = wr0[i8], w1 = wr1[i8];
                    #pragma unroll
                    for (int r=0;r<4;r++){
                        const float* x = xf + r*512 + i8*8;
                        fma8(x, w0.x,w0.y,w0.z,w0.w, a0[r]);
                        fma8(x, w1.x,w1.y,w1.z,w1.w, a1[r]);
                    }
                }
            } else {
                const float4* wr0 = (const float4*)((const float*)W + (size_t)t*EMBED);
                const float4* wr1 = (const float4*)((const float*)W + (size_t)(t+256)*EMBED);
                for (int i4=0;i4<128;i4++){
                    float4 w0 = wr0[i4], w1 = wr1[i4];
                    #pragma unroll
                    for (int r=0;r<4;r++){
                        const float* x = xf + r*512 + i4*4;
                        fma4f(x, w0, a0[r]);
                        fma4f(x, w1, a1[r]);
                    }
                }
            }
            float b0 = fb ? ((const float*)Bb)[t]     : bf2f(((const u16*)Bb)[t]);
            float b1 = fb ? ((const float*)Bb)[t+256] : bf2f(((const u16*)Bb)[t+256]);
            #pragma unroll
            for (int r=0;r<4;r++){
                int row = g*4+r;
                int c0 = t, c1 = t+256;
                ps[(row*8+(c0>>6))*65 + (c0&63)] = a0[r]+b0;
                ps[(row*8+(c1>>6))*65 + (c1&63)] = a1[r]+b1;
            }
            __syncthreads();
        }
    }

    if (which == 2){
        __syncthreads();
        // V: store raw bf16 (32 elems per thread)
        int hr = t>>1, half = t&1;
        int row = hr>>3, head = hr&7;
        const float* src = ps + hr*65 + half*32;
        u16* dst = Vb + (size_t)(r0+row)*EMBED + head*64 + half*32;
        #pragma unroll
        for (int j8=0;j8<4;j8++){
            uint4 v;
            v.x = pack2(src[j8*8+0],src[j8*8+1]); v.y = pack2(src[j8*8+2],src[j8*8+3]);
            v.z = pack2(src[j8*8+4],src[j8*8+5]); v.w = pack2(src[j8*8+6],src[j8*8+7]);
            ((uint4*)dst)[j8] = v;
        }
        return;
    }

    // ---------- centroid scan: register-tiled LDS GEMM + row argmax ----------
    u32 fc = sniffp(cen);
    float* centT = (float*)ubuf;            // [64 dims][68] f32, transposed tile
    int rg = t>>3, cg = t&7;                // 4-row group 0..31, 8-cent group 0..7
    float best[4] = {-3.4e38f,-3.4e38f,-3.4e38f,-3.4e38f};
    int   bidx[4] = {0,0,0,0};
    for (int tt=0; tt<8; tt++){
        __syncthreads();                     // ps ready (tt=0) / prev tile readers done
        for (int e=t; e<4096; e+=256){       // e = j*64 + k  (coalesced global read)
            int j = e>>6, k = e&63;
            float v = fc ? ((const float*)cen)[(size_t)(tt*64+j)*HD + k]
                         : bf2f(((const u16*)cen)[(size_t)(tt*64+j)*HD + k]);
            centT[k*68 + j] = v;
        }
        __syncthreads();
        float acc[4][8];
        #pragma unroll
        for (int j=0;j<4;j++)
            #pragma unroll
            for (int c=0;c<8;c++) acc[j][c]=0.f;
        const float* pr = ps + (rg*4)*65;
        for (int k=0;k<64;k++){
            float r0v = pr[k];
            float r1v = pr[65+k];
            float r2v = pr[130+k];
            float r3v = pr[195+k];
            const float4* cp = (const float4*)(centT + k*68 + cg*8);
            float4 c0 = cp[0], c1 = cp[1];
            acc[0][0]+=r0v*c0.x; acc[0][1]+=r0v*c0.y; acc[0][2]+=r0v*c0.z; acc[0][3]+=r0v*c0.w;
            acc[0][4]+=r0v*c1.x; acc[0][5]+=r0v*c1.y; acc[0][6]+=r0v*c1.z; acc[0][7]+=r0v*c1.w;
            acc[1][0]+=r1v*c0.x; acc[1][1]+=r1v*c0.y; acc[1][2]+=r1v*c0.z; acc[1][3]+=r1v*c0.w;
            acc[1][4]+=r1v*c1.x; acc[1][5]+=r1v*c1.y; acc[1][6]+=r1v*c1.z; acc[1][7]+=r1v*c1.w;
            acc[2][0]+=r2v*c0.x; acc[2][1]+=r2v*c0.y; acc[2][2]+=r2v*c0.z; acc[2][3]+=r2v*c0.w;
            acc[2][4]+=r2v*c1.x; acc[2][5]+=r2v*c1.y; acc[2][6]+=r2v*c1.z; acc[2][7]+=r2v*c1.w;
            acc[3][0]+=r3v*c0.x; acc[3][1]+=r3v*c0.y; acc[3][2]+=r3v*c0.z; acc[3][3]+=r3v*c0.w;
            acc[3][4]+=r3v*c1.x; acc[3][5]+=r3v*c1.y; acc[3][6]+=r3v*c1.z; acc[3][7]+=r3v*c1.w;
        }
        #pragma unroll
        for (int j=0;j<4;j++){
            #pragma unroll
            for (int c=0;c<8;c++){
                int gi = tt*64 + cg*8 + c;   // ascending within thread -> strict > keeps first
                if (acc[j][c] > best[j]){ best[j]=acc[j][c]; bidx[j]=gi; }
            }
        }
    }
    #pragma unroll
    for (int j=0;j<4;j++){ bvl[rg*4+j][cg]=best[j]; bil[rg*4+j][cg]=bidx[j]; }
    // per-head sumsq partials (ps intact)
    {
        int hr = t>>1, half = t&1;
        const float* src = ps + hr*65 + half*32;
        float ss=0.f;
        #pragma unroll
        for (int d=0;d<32;d++) ss += src[d]*src[d];
        nrm2[hr][half]=ss;
    }
    __syncthreads();
    if (t < 128){
        int hr = t;
        invn[hr] = 1.f / fmaxf(sqrtf(nrm2[hr][0]+nrm2[hr][1]), 1e-12f);
        float bv = bvl[hr][0]; int bi = bil[hr][0];
        #pragma unroll
        for (int g=1; g<8; g++){             // disjoint index sets: (>, ==&&<) merge = np.argmax
            float ov = bvl[hr][g]; int oi = bil[hr][g];
            if (ov > bv || (ov == bv && oi < bi)){ bv = ov; bi = oi; }
        }
        u16* bins = (which==0) ? qbin : kbin;
        int token = r0 + (hr>>3), head = hr&7;
        bins[head*NTOK + token] = (u16)bi;
    }
    __syncthreads();
    // normalized store: Q -> outQ (query dtype), K -> Kb (bf16)
    {
        int hr = t>>1, half = t&1;
        float inv = invn[hr];
        const float* src = ps + hr*65 + half*32;
        int row = hr>>3, head = hr&7;
        size_t off = (size_t)(r0+row)*EMBED + head*64 + half*32;
        if (which == 1){
            u16* dst = Kb + off;
            #pragma unroll
            for (int j8=0;j8<4;j8++){
                uint4 v;
                v.x = pack2(src[j8*8+0]*inv, src[j8*8+1]*inv);
                v.y = pack2(src[j8*8+2]*inv, src[j8*8+3]*inv);
                v.z = pack2(src[j8*8+4]*inv, src[j8*8+5]*inv);
                v.w = pack2(src[j8*8+6]*inv, src[j8*8+7]*inv);
                ((uint4*)dst)[j8] = v;
            }
        } else if (!fx){
            u16* dst = (u16*)outQ + off;
            #pragma unroll
            for (int j8=0;j8<4;j8++){
                uint4 v;
                v.x = pack2(src[j8*8+0]*inv, src[j8*8+1]*inv);
                v.y = pack2(src[j8*8+2]*inv, src[j8*8+3]*inv);
                v.z = pack2(src[j8*8+4]*inv, src[j8*8+5]*inv);
                v.w = pack2(src[j8*8+6]*inv, src[j8*8+7]*inv);
                ((uint4*)dst)[j8] = v;
            }
        } else {
            float* dst = (float*)outQ + off;
            #pragma unroll
            for (int j=0;j<32;j++) dst[j] = src[j]*inv;
        }
    }
}

// ============ K2: attention ============
// grid 2048 (one block per query token), 4 waves x 2 heads. Qb read from d_out row q,
// AO written back to the same row (race-free). Wave-level scan, minimal barriers.
__global__ __launch_bounds__(256) void attn_kernel(
    const void* __restrict__ query,
    const u16* __restrict__ Kb, const u16* __restrict__ Vb,
    const u16* __restrict__ qbin, const u16* __restrict__ kbin,
    void* __restrict__ out)
{
    u32 fq = sniffp(query);
    int q = blockIdx.x, t = threadIdx.x;
    int wave = t>>6, lane = t&63;
    __shared__ float qs[512];
    __shared__ float sc[4][256];
    __shared__ u16   sel[4][256];

    if (!fq){
        u32 u = ((const u32*)out)[(size_t)q*256 + t];
        qs[2*t] = lof(u); qs[2*t+1] = hif(u);
    } else {
        float2 f = ((const float2*)out)[(size_t)q*256 + t];
        qs[2*t] = f.x; qs[2*t+1] = f.y;
    }
    __syncthreads();

    for (int hh=0; hh<2; hh++){
        int h = wave*2 + hh;
        int myqb = qbin[h*NTOK + q];
        const uint4* kbp = (const uint4*)(kbin + h*NTOK + lane*32);
        u32 fl = 0;
        #pragma unroll
        for (int w4=0; w4<4; w4++){
            uint4 kw = kbp[w4];
            u32 arr[4] = {kw.x, kw.y, kw.z, kw.w};
            #pragma unroll
            for (int e=0;e<4;e++){
                int b0 = (int)(arr[e] & 0xffff), b1 = (int)(arr[e] >> 16);
                int d0 = (myqb - b0) & (NBINS-1), d1 = (myqb - b1) & (NBINS-1);
                if (d0 <= 1 || d0 >= NBINS-1) fl |= 1u << (w4*8 + e*2);
                if (d1 <= 1 || d1 >= NBINS-1) fl |= 1u << (w4*8 + e*2 + 1);
            }
        }
        int cnt = __popc(fl);
        int sum = cnt;
        #pragma unroll
        for (int off=1; off<64; off<<=1){
            int v = __shfl_up(sum, off, 64);
            if (lane >= off) sum += v;
        }
        int total = __shfl(sum, 63, 64);
        int r = sum - cnt;
        if (total){
            u32 f2 = fl;
            while (f2){
                int j = __ffs(f2) - 1; f2 &= f2 - 1;
                if (r < MAXSEL) sel[wave][r] = (u16)(lane*32 + j);
                r++;
            }
        } else {
            #pragma unroll
            for (int kq=0;kq<4;kq++) sel[wave][lane*4+kq] = (u16)(lane*4+kq);
        }
        int L = total ? min(total, MAXSEL) : MAXSEL;
        __syncthreads();
        const float* qh = qs + h*64;
        float mloc = -3.4e38f;
        for (int jj=lane; jj<L; jj+=64){
            int kkey = sel[wave][jj];
            const uint4* kr = (const uint4*)(Kb + (size_t)kkey*EMBED + h*64);
            float acc = 0.f;
            #pragma unroll
            for (int p=0;p<8;p++){ uint4 u = kr[p]; fma8(qh+p*8, u.x,u.y,u.z,u.w, acc); }
            float s = acc * 0.125f;
            sc[wave][jj] = s;
            mloc = fmaxf(mloc, s);
        }
        #pragma unroll
        for (int off=32; off; off>>=1) mloc = fmaxf(mloc, __shfl_xor(mloc, off, 64));
        float ssum = 0.f;
        for (int jj=lane; jj<L; jj+=64){
            float e = __expf(sc[wave][jj] - mloc);
            sc[wave][jj] = e; ssum += e;
        }
        #pragma unroll
        for (int off=32; off; off>>=1) ssum += __shfl_xor(ssum, off, 64);
        float inv = 1.f / fmaxf(ssum, 1e-37f);
        __syncthreads();
        float acc = 0.f;
        for (int j=0; j<L; j++){
            int kkey = sel[wave][j];
            acc += sc[wave][j] * bf2f(Vb[(size_t)kkey*EMBED + h*64 + lane]);
        }
        float o = acc * inv;
        if (!fq) ((u16*)out)[(size_t)q*EMBED + h*64 + lane] = f2b(o);
        else     ((float*)out)[(size_t)q*EMBED + h*64 + lane] = o;
        __syncthreads();
    }
}

// ============ K3: output projection (MFMA), in place on d_out ============
// grid 128: 16 rows/block, staged fully before overwrite.
__global__ __launch_bounds__(256) void oproj_kernel(
    void* __restrict__ out, const void* __restrict__ Wo, const void* __restrict__ bo)
{
    u32 fq = sniffp(out);
    u32 fw = sniffp(Wo), fb = sniffp(bo);
    int r0 = blockIdx.x * 16;
    int t = threadIdx.x;
    __shared__ u16  ab[16*520];
    __shared__ float xf[4][512];

    if (!(fq|fw|fb)){
        {
            int row = t>>4, seg = t&15;
            const uint4* src = (const uint4*)((const u16*)out + (size_t)(r0+row)*EMBED + seg*32);
            uint4* dst = (uint4*)(ab + row*520 + seg*32);
            dst[0] = src[0]; dst[1] = src[1];
        }
        __syncthreads();
        int lane = t&63, wave = t>>6;
        int m = lane&15, quad = lane>>4;
        int obase = wave*128;
        f32x4 acc[8];
        #pragma unroll
        for (int i=0;i<8;i++){ f32x4 z = {0.f,0.f,0.f,0.f}; acc[i] = z; }
        const u16* arow = ab + m*520 + quad*8;
        const u16* wp = (const u16*)Wo;
        for (int k=0;k<16;k++){
            int i0 = k*32;
            s16x8 a = *(const s16x8*)(arow + i0);
            #pragma unroll
            for (int tile=0;tile<8;tile++){
                int o = obase + tile*16 + m;
                s16x8 b = *(const s16x8*)(wp + (size_t)o*EMBED + i0 + quad*8);
                acc[tile] = __builtin_amdgcn_mfma_f32_16x16x32_bf16(a, b, acc[tile], 0, 0, 0);
            }
        }
        #pragma unroll
        for (int tile=0;tile<8;tile++){
            int o = obase + tile*16 + m;
            float bias = bf2f(((const u16*)bo)[o]);
            #pragma unroll
            for (int reg=0;reg<4;reg++){
                int row = quad*4 + reg;
                ((u16*)out)[(size_t)(r0+row)*EMBED + o] = f2b(acc[tile][reg] + bias);
            }
        }
    } else {
        for (int g=0; g<4; g++){
            {
                float* xr = &xf[0][0] + t*8;
                if (!fq){
                    uint4 u = ((const uint4*)((const u16*)out + (size_t)(r0+g*4)*EMBED))[t];
                    xr[0]=lof(u.x); xr[1]=hif(u.x); xr[2]=lof(u.y); xr[3]=hif(u.y);
                    xr[4]=lof(u.z); xr[5]=hif(u.z); xr[6]=lof(u.w); xr[7]=hif(u.w);
                } else {
                    const float4* A4 = (const float4*)((const float*)out + (size_t)(r0+g*4)*EMBED);
                    float4 fa = A4[2*t], fb2 = A4[2*t+1];
                    xr[0]=fa.x; xr[1]=fa.y; xr[2]=fa.z; xr[3]=fa.w;
                    xr[4]=fb2.x; xr[5]=fb2.y; xr[6]=fb2.z; xr[7]=fb2.w;
                }
            }
            __syncthreads();
            float a0[4]={0.f,0.f,0.f,0.f}, a1[4]={0.f,0.f,0.f,0.f};
            if (!fw){
                const uint4* wr0 = (const uint4*)((const u16*)Wo + (size_t)t*EMBED);
                const uint4* wr1 = (const uint4*)((const u16*)Wo + (size_t)(t+256)*EMBED);
                for (int i8=0;i8<64;i8++){
                    uint4 w0 = wr0[i8], w1 = wr1[i8];
                    #pragma unroll
                    for (int r=0;r<4;r++){
                        const float* x = &xf[r][i8*8];
                        fma8(x, w0.x,w0.y,w0.z,w0.w, a0[r]);
                        fma8(x, w1.x,w1.y,w1.z,w1.w, a1[r]);
                    }
                }
            } else {
                const float4* wr0 = (const float4*)((const float*)Wo + (size_t)t*EMBED);
                const float4* wr1 = (const float4*)((const float*)Wo + (size_t)(t+256)*EMBED);
                for (int i4=0;i4<128;i4++){
                    float4 w0 = wr0[i4], w1 = wr1[i4];
                    #pragma unroll
                    for (int r=0;r<4;r++){
                        const float* x = &xf[r][i4*4];
                        fma4f(x, w0, a0[r]);
                        fma4f(x, w1, a1[r]);
                    }
                }
            }
            float b0 = fb ? ((const float*)bo)[t]     : bf2f(((const u16*)bo)[t]);
            float b1 = fb ? ((const float*)bo)[t+256] : bf2f(((const u16*)bo)[t+256]);
            if (!fq){
                u16* o = (u16*)out;
                #pragma unroll
                for (int r=0;r<4;r++){
                    o[(size_t)(r0+g*4+r)*EMBED + t]       = f2b(a0[r]+b0);
                    o[(size_t)(r0+g*4+r)*EMBED + t + 256] = f2b(a1[r]+b1);
                }
            } else {
                float* o = (float*)out;
                #pragma unroll
                for (int r=0;r<4;r++){
                    o[(size_t)(r0+g*4+r)*EMBED + t]       = a0[r]+b0;
                    o[(size_t)(r0+g*4+r)*EMBED + t + 256] = a1[r]+b1;
                }
            }
            __syncthreads();
        }
    }
}

extern "C" void kernel_launch(void* const* d_in, const int* in_sizes, int n_in,
                              void* d_out, int out_size, void* d_ws, size_t ws_size,
                              hipStream_t stream)
{
    const void* query = d_in[0];
    const void* key   = d_in[1];
    const void* value = d_in[2];
    const void* Wq = d_in[3];
    const void* bq = d_in[4];
    const void* Wk = d_in[5];
    const void* bk = d_in[6];
    const void* Wv = d_in[7];
    const void* bv = d_in[8];
    const void* Wo = d_in[9];
    const void* bo = d_in[10];
    const void* cen = d_in[11];

    // ws layout (4,259,840 B total — round-7/8-proven footprint):
    //   [0, 32K)        qbin u16[16384]
    //   [32K, 64K)      kbin u16[16384]
    //   [64K, 64K+2M)   Kb bf16 (normalized)
    //   [64K+2M, +2M)   Vb bf16 (raw)
    char* ws = (char*)d_ws;
    u16* qbin = (u16*)ws;
    u16* kbin = (u16*)(ws + 32768);
    u16* Kb   = (u16*)(ws + 65536);
    u16* Vb   = (u16*)(ws + 65536 + (size_t)2*1024*1024);

    projqkv_kernel<<<dim3(128,3), 256, 0, stream>>>(query,key,value,Wq,bq,Wk,bk,Wv,bv,cen,
                                                    d_out,Kb,Vb,qbin,kbin);
    attn_kernel<<<2048, 256, 0, stream>>>(query,Kb,Vb,qbin,kbin,d_out);
    oproj_kernel<<<128, 256, 0, stream>>>(d_out,Wo,bo);
}

// Round 10
// 439.068 us; speedup vs baseline: 2.1984x; 1.2311x over previous
//
#include <hip/hip_runtime.h>
#include <hip/hip_bf16.h>

#define NTOK 2048
#define EMBED 512
#define NHEADS 8
#define HD 64
#define NBINS 512
#define MAXSEL 256

typedef unsigned short u16;
typedef unsigned int u32;
typedef short s16x8 __attribute__((ext_vector_type(8)));
typedef float f32x4 __attribute__((ext_vector_type(4)));

__device__ __forceinline__ float lof(u32 u){ return __uint_as_float(u << 16); }
__device__ __forceinline__ float hif(u32 u){ return __uint_as_float(u & 0xffff0000u); }
__device__ __forceinline__ float bf2f(u16 u){ return __uint_as_float(((u32)u) << 16); }
__device__ __forceinline__ u16 f2b(float f){
    __hip_bfloat16 h = __float2bfloat16(f);
    return *(u16*)&h;
}
__device__ __forceinline__ u32 pack2(float lo, float hi){
    return (u32)f2b(lo) | ((u32)f2b(hi) << 16);
}
__device__ __forceinline__ void fma8(const float* x, u32 ux, u32 uy, u32 uz, u32 uw, float& a){
    a += x[0]*lof(ux) + x[1]*hif(ux) + x[2]*lof(uy) + x[3]*hif(uy)
       + x[4]*lof(uz) + x[5]*hif(uz) + x[6]*lof(uw) + x[7]*hif(uw);
}
__device__ __forceinline__ void fma4f(const float* x, float4 w, float& a){
    a += x[0]*w.x + x[1]*w.y + x[2]*w.z + x[3]*w.w;
}

// Inline per-block dtype sniff: read 64 even u16s of the tensor as bf16.
// f32 data -> low mantissa halves -> random bf16 exponents -> max>100 w.p. ~1.
// bf16 data here (|x|<6) -> max<10. All threads same samples -> uniform branch.
__device__ __forceinline__ u32 sniffp(const void* p){
    const u16* s = (const u16*)p;
    float m = 0.f;
    #pragma unroll
    for (int k=0; k<64; k++) m = fmaxf(m, fabsf(bf2f(s[2*k])));
    return (m > 100.f) ? 1u : 0u;
}

// ============ K1: QKV projection + per-head norm + centroid bins ============
// grid (128, 3): 16 tokens/block, y: 0=Q 1=K 2=V. block 256.
// f32 path: X-tile staged in ps region; W streamed via LDS k-slices (coalesced);
// 16x2 accumulators per thread; results then overwrite ps; scan as before.
__global__ __launch_bounds__(256) void projqkv_kernel(
    const void* __restrict__ Xq, const void* __restrict__ Xk, const void* __restrict__ Xv,
    const void* __restrict__ Wq, const void* __restrict__ bq,
    const void* __restrict__ Wk, const void* __restrict__ bk,
    const void* __restrict__ Wv, const void* __restrict__ bv,
    const void* __restrict__ cen,
    void* __restrict__ outQ,                 // d_out: normalized Q staging (query dtype)
    u16* __restrict__ Kb, u16* __restrict__ Vb,
    u16* __restrict__ qbin, u16* __restrict__ kbin)
{
    int which = blockIdx.y;
    const void *X, *W, *Bb;
    if (which==0){ X=Xq; W=Wq; Bb=bq; }
    else if (which==1){ X=Xk; W=Wk; Bb=bk; }
    else { X=Xv; W=Wv; Bb=bv; }
    u32 fx = sniffp(X), fw = sniffp(W), fb = sniffp(Bb);
    int r0 = blockIdx.x * 16;
    int t = threadIdx.x;

    // ubuf phases: [GEMM-mfma] xsb 16x520 u16 (16640 B) | [GEMM-f32] wslice 8x520 f32 (16640 B)
    //              [scan] centT 64x68 f32 (17408 B)
    __shared__ __align__(16) char ubuf[17408];
    __shared__ float ps[128*65];         // f32 projections [(tokrow*8+head)][65]; f32 path also
                                         // uses it as X staging [16][516] during GEMM
    __shared__ float nrm2[128][2];
    __shared__ float invn[128];
    __shared__ float bvl[128][8];
    __shared__ int   bil[128][8];

    if (!(fx|fw|fb)){
        // ---------- MFMA path (all-bf16) ----------
        u16* xsb = (u16*)ubuf;
        {
            int row = t>>4, seg = t&15;
            const uint4* src = (const uint4*)((const u16*)X + (size_t)(r0+row)*EMBED + seg*32);
            uint4* dst = (uint4*)(xsb + row*520 + seg*32);
            dst[0] = src[0]; dst[1] = src[1];
        }
        __syncthreads();
        int lane = t&63, wave = t>>6;
        int m = lane&15, quad = lane>>4;
        int obase = wave*128;
        f32x4 acc[8];
        #pragma unroll
        for (int i=0;i<8;i++){ f32x4 z = {0.f,0.f,0.f,0.f}; acc[i] = z; }
        const u16* arow = xsb + m*520 + quad*8;
        const u16* wp = (const u16*)W;
        for (int k=0;k<16;k++){
            int i0 = k*32;
            s16x8 a = *(const s16x8*)(arow + i0);
            #pragma unroll
            for (int tile=0;tile<8;tile++){
                int o = obase + tile*16 + m;
                s16x8 b = *(const s16x8*)(wp + (size_t)o*EMBED + i0 + quad*8);
                acc[tile] = __builtin_amdgcn_mfma_f32_16x16x32_bf16(a, b, acc[tile], 0, 0, 0);
            }
        }
        #pragma unroll
        for (int tile=0;tile<8;tile++){
            int o = obase + tile*16 + m;
            float bias = bf2f(((const u16*)Bb)[o]);
            int head = o>>6, c = o&63;
            #pragma unroll
            for (int reg=0;reg<4;reg++){
                int row = quad*4 + reg;
                ps[(row*8+head)*65 + c] = acc[tile][reg] + bias;
            }
        }
    } else {
        // ---------- f32 path: single-pass, LDS-staged W ----------
        float* xstage = ps;                    // [16][516] f32 (8256 <= 8320 floats)
        // Phase A: stage X tile (coalesced, 16B/lane)
        for (int i=t; i<2048; i+=256){         // 2048 float4 = 16 rows x 128
            int row = i>>7, c4 = i&127;
            float4 v;
            if (!fx){
                const u32* xp = (const u32*)((const u16*)X + (size_t)(r0+row)*EMBED);
                u32 a = xp[c4*2], b = xp[c4*2+1];
                v = make_float4(lof(a), hif(a), lof(b), hif(b));
            } else {
                v = ((const float4*)((const float*)X + (size_t)(r0+row)*EMBED))[c4];
            }
            *(float4*)(xstage + row*516 + c4*4) = v;
        }
        float acc2[16][2];
        #pragma unroll
        for (int r=0;r<16;r++){ acc2[r][0]=0.f; acc2[r][1]=0.f; }
        float* wslice = (float*)ubuf;          // [8][520] f32, k-major
        for (int k0=0; k0<512; k0+=8){
            __syncthreads();                   // xstage ready (k0=0) / prev slice consumed
            for (int j=t; j<1024; j+=256){     // j = o*2+half; 16B/lane, 32B per o-row
                int o = j>>1, half = j&1;
                float4 wv;
                if (!fw){
                    const u32* wp2 = (const u32*)((const u16*)W + (size_t)o*EMBED + k0 + half*4);
                    u32 a = wp2[0], b = wp2[1];
                    wv = make_float4(lof(a), hif(a), lof(b), hif(b));
                } else {
                    wv = *(const float4*)((const float*)W + (size_t)o*EMBED + k0 + half*4);
                }
                int kb = half*4;
                wslice[(kb+0)*520 + o] = wv.x;
                wslice[(kb+1)*520 + o] = wv.y;
                wslice[(kb+2)*520 + o] = wv.z;
                wslice[(kb+3)*520 + o] = wv.w;
            }
            __syncthreads();
            float w0[8], w1[8];
            #pragma unroll
            for (int kk=0;kk<8;kk++){          // b32 reads, lanes consecutive: conflict-free
                w0[kk] = wslice[kk*520 + t];
                w1[kk] = wslice[kk*520 + t + 256];
            }
            #pragma unroll
            for (int r=0;r<16;r++){
                const float* x = xstage + r*516 + k0;   // broadcast b128 reads
                float4 x0 = *(const float4*)(x);
                float4 x1 = *(const float4*)(x+4);
                acc2[r][0] += x0.x*w0[0]+x0.y*w0[1]+x0.z*w0[2]+x0.w*w0[3]
                            + x1.x*w0[4]+x1.y*w0[5]+x1.z*w0[6]+x1.w*w0[7];
                acc2[r][1] += x0.x*w1[0]+x0.y*w1[1]+x0.z*w1[2]+x0.w*w1[3]
                            + x1.x*w1[4]+x1.y*w1[5]+x1.z*w1[6]+x1.w*w1[7];
            }
        }
        __syncthreads();                       // all xstage reads done before ps overwrite
        float b0 = fb ? ((const float*)Bb)[t]     : bf2f(((const u16*)Bb)[t]);
        float b1 = fb ? ((const float*)Bb)[t+256] : bf2f(((const u16*)Bb)[t+256]);
        #pragma unroll
        for (int r=0;r<16;r++){
            int o0 = t, o1 = t+256;
            ps[(r*8+(o0>>6))*65 + (o0&63)] = acc2[r][0]+b0;
            ps[(r*8+(o1>>6))*65 + (o1&63)] = acc2[r][1]+b1;
        }
    }

    if (which == 2){
        __syncthreads();
        // V: store raw bf16 (32 elems per thread)
        int hr = t>>1, half = t&1;
        int row = hr>>3, head = hr&7;
        const float* src = ps + hr*65 + half*32;
        u16* dst = Vb + (size_t)(r0+row)*EMBED + head*64 + half*32;
        #pragma unroll
        for (int j8=0;j8<4;j8++){
            uint4 v;
            v.x = pack2(src[j8*8+0],src[j8*8+1]); v.y = pack2(src[j8*8+2],src[j8*8+3]);
            v.z = pack2(src[j8*8+4],src[j8*8+5]); v.w = pack2(src[j8*8+6],src[j8*8+7]);
            ((uint4*)dst)[j8] = v;
        }
        return;
    }

    // ---------- centroid scan: register-tiled LDS GEMM + row argmax ----------
    u32 fc = sniffp(cen);
    float* centT = (float*)ubuf;            // [64 dims][68] f32, transposed tile
    int rg = t>>3, cg = t&7;                // 4-row group 0..31, 8-cent group 0..7
    float best[4] = {-3.4e38f,-3.4e38f,-3.4e38f,-3.4e38f};
    int   bidx[4] = {0,0,0,0};
    for (int tt=0; tt<8; tt++){
        __syncthreads();                     // ps ready (tt=0) / prev tile readers done
        for (int e=t; e<4096; e+=256){       // e = j*64 + k  (coalesced global read)
            int j = e>>6, k = e&63;
            float v = fc ? ((const float*)cen)[(size_t)(tt*64+j)*HD + k]
                         : bf2f(((const u16*)cen)[(size_t)(tt*64+j)*HD + k]);
            centT[k*68 + j] = v;
        }
        __syncthreads();
        float acc[4][8];
        #pragma unroll
        for (int j=0;j<4;j++)
            #pragma unroll
            for (int c=0;c<8;c++) acc[j][c]=0.f;
        const float* pr = ps + (rg*4)*65;
        for (int k=0;k<64;k++){
            float r0v = pr[k];
            float r1v = pr[65+k];
            float r2v = pr[130+k];
            float r3v = pr[195+k];
            const float4* cp = (const float4*)(centT + k*68 + cg*8);
            float4 c0 = cp[0], c1 = cp[1];
            acc[0][0]+=r0v*c0.x; acc[0][1]+=r0v*c0.y; acc[0][2]+=r0v*c0.z; acc[0][3]+=r0v*c0.w;
            acc[0][4]+=r0v*c1.x; acc[0][5]+=r0v*c1.y; acc[0][6]+=r0v*c1.z; acc[0][7]+=r0v*c1.w;
            acc[1][0]+=r1v*c0.x; acc[1][1]+=r1v*c0.y; acc[1][2]+=r1v*c0.z; acc[1][3]+=r1v*c0.w;
            acc[1][4]+=r1v*c1.x; acc[1][5]+=r1v*c1.y; acc[1][6]+=r1v*c1.z; acc[1][7]+=r1v*c1.w;
            acc[2][0]+=r2v*c0.x; acc[2][1]+=r2v*c0.y; acc[2][2]+=r2v*c0.z; acc[2][3]+=r2v*c0.w;
            acc[2][4]+=r2v*c1.x; acc[2][5]+=r2v*c1.y; acc[2][6]+=r2v*c1.z; acc[2][7]+=r2v*c1.w;
            acc[3][0]+=r3v*c0.x; acc[3][1]+=r3v*c0.y; acc[3][2]+=r3v*c0.z; acc[3][3]+=r3v*c0.w;
            acc[3][4]+=r3v*c1.x; acc[3][5]+=r3v*c1.y; acc[3][6]+=r3v*c1.z; acc[3][7]+=r3v*c1.w;
        }
        #pragma unroll
        for (int j=0;j<4;j++){
            #pragma unroll
            for (int c=0;c<8;c++){
                int gi = tt*64 + cg*8 + c;   // ascending within thread -> strict > keeps first
                if (acc[j][c] > best[j]){ best[j]=acc[j][c]; bidx[j]=gi; }
            }
        }
    }
    #pragma unroll
    for (int j=0;j<4;j++){ bvl[rg*4+j][cg]=best[j]; bil[rg*4+j][cg]=bidx[j]; }
    // per-head sumsq partials (ps intact)
    {
        int hr = t>>1, half = t&1;
        const float* src = ps + hr*65 + half*32;
        float ss=0.f;
        #pragma unroll
        for (int d=0;d<32;d++) ss += src[d]*src[d];
        nrm2[hr][half]=ss;
    }
    __syncthreads();
    if (t < 128){
        int hr = t;
        invn[hr] = 1.f / fmaxf(sqrtf(nrm2[hr][0]+nrm2[hr][1]), 1e-12f);
        float bv = bvl[hr][0]; int bi = bil[hr][0];
        #pragma unroll
        for (int g=1; g<8; g++){             // disjoint index sets: (>, ==&&<) merge = np.argmax
            float ov = bvl[hr][g]; int oi = bil[hr][g];
            if (ov > bv || (ov == bv && oi < bi)){ bv = ov; bi = oi; }
        }
        u16* bins = (which==0) ? qbin : kbin;
        int token = r0 + (hr>>3), head = hr&7;
        bins[head*NTOK + token] = (u16)bi;
    }
    __syncthreads();
    // normalized store: Q -> outQ (query dtype), K -> Kb (bf16)
    {
        int hr = t>>1, half = t&1;
        float inv = invn[hr];
        const float* src = ps + hr*65 + half*32;
        int row = hr>>3, head = hr&7;
        size_t off = (size_t)(r0+row)*EMBED + head*64 + half*32;
        if (which == 1){
            u16* dst = Kb + off;
            #pragma unroll
            for (int j8=0;j8<4;j8++){
                uint4 v;
                v.x = pack2(src[j8*8+0]*inv, src[j8*8+1]*inv);
                v.y = pack2(src[j8*8+2]*inv, src[j8*8+3]*inv);
                v.z = pack2(src[j8*8+4]*inv, src[j8*8+5]*inv);
                v.w = pack2(src[j8*8+6]*inv, src[j8*8+7]*inv);
                ((uint4*)dst)[j8] = v;
            }
        } else if (!fx){
            u16* dst = (u16*)outQ + off;
            #pragma unroll
            for (int j8=0;j8<4;j8++){
                uint4 v;
                v.x = pack2(src[j8*8+0]*inv, src[j8*8+1]*inv);
                v.y = pack2(src[j8*8+2]*inv, src[j8*8+3]*inv);
                v.z = pack2(src[j8*8+4]*inv, src[j8*8+5]*inv);
                v.w = pack2(src[j8*8+6]*inv, src[j8*8+7]*inv);
                ((uint4*)dst)[j8] = v;
            }
        } else {
            float* dst = (float*)outQ + off;
            #pragma unroll
            for (int j=0;j<32;j++) dst[j] = src[j]*inv;
        }
    }
}

// ============ K2: attention ============
// grid 2048 (one block per query token), 4 waves x 2 heads. Qb read from d_out row q,
// AO written back to the same row (race-free). Wave-level scan, minimal barriers.
__global__ __launch_bounds__(256) void attn_kernel(
    const void* __restrict__ query,
    const u16* __restrict__ Kb, const u16* __restrict__ Vb,
    const u16* __restrict__ qbin, const u16* __restrict__ kbin,
    void* __restrict__ out)
{
    u32 fq = sniffp(query);
    int q = blockIdx.x, t = threadIdx.x;
    int wave = t>>6, lane = t&63;
    __shared__ float qs[512];
    __shared__ float sc[4][256];
    __shared__ u16   sel[4][256];

    if (!fq){
        u32 u = ((const u32*)out)[(size_t)q*256 + t];
        qs[2*t] = lof(u); qs[2*t+1] = hif(u);
    } else {
        float2 f = ((const float2*)out)[(size_t)q*256 + t];
        qs[2*t] = f.x; qs[2*t+1] = f.y;
    }
    __syncthreads();

    for (int hh=0; hh<2; hh++){
        int h = wave*2 + hh;
        int myqb = qbin[h*NTOK + q];
        const uint4* kbp = (const uint4*)(kbin + h*NTOK + lane*32);
        u32 fl = 0;
        #pragma unroll
        for (int w4=0; w4<4; w4++){
            uint4 kw = kbp[w4];
            u32 arr[4] = {kw.x, kw.y, kw.z, kw.w};
            #pragma unroll
            for (int e=0;e<4;e++){
                int b0 = (int)(arr[e] & 0xffff), b1 = (int)(arr[e] >> 16);
                int d0 = (myqb - b0) & (NBINS-1), d1 = (myqb - b1) & (NBINS-1);
                if (d0 <= 1 || d0 >= NBINS-1) fl |= 1u << (w4*8 + e*2);
                if (d1 <= 1 || d1 >= NBINS-1) fl |= 1u << (w4*8 + e*2 + 1);
            }
        }
        int cnt = __popc(fl);
        int sum = cnt;
        #pragma unroll
        for (int off=1; off<64; off<<=1){
            int v = __shfl_up(sum, off, 64);
            if (lane >= off) sum += v;
        }
        int total = __shfl(sum, 63, 64);
        int r = sum - cnt;
        if (total){
            u32 f2 = fl;
            while (f2){
                int j = __ffs(f2) - 1; f2 &= f2 - 1;
                if (r < MAXSEL) sel[wave][r] = (u16)(lane*32 + j);
                r++;
            }
        } else {
            #pragma unroll
            for (int kq=0;kq<4;kq++) sel[wave][lane*4+kq] = (u16)(lane*4+kq);
        }
        int L = total ? min(total, MAXSEL) : MAXSEL;
        __syncthreads();
        const float* qh = qs + h*64;
        float mloc = -3.4e38f;
        for (int jj=lane; jj<L; jj+=64){
            int kkey = sel[wave][jj];
            const uint4* kr = (const uint4*)(Kb + (size_t)kkey*EMBED + h*64);
            float acc = 0.f;
            #pragma unroll
            for (int p=0;p<8;p++){ uint4 u = kr[p]; fma8(qh+p*8, u.x,u.y,u.z,u.w, acc); }
            float s = acc * 0.125f;
            sc[wave][jj] = s;
            mloc = fmaxf(mloc, s);
        }
        #pragma unroll
        for (int off=32; off; off>>=1) mloc = fmaxf(mloc, __shfl_xor(mloc, off, 64));
        float ssum = 0.f;
        for (int jj=lane; jj<L; jj+=64){
            float e = __expf(sc[wave][jj] - mloc);
            sc[wave][jj] = e; ssum += e;
        }
        #pragma unroll
        for (int off=32; off; off>>=1) ssum += __shfl_xor(ssum, off, 64);
        float inv = 1.f / fmaxf(ssum, 1e-37f);
        __syncthreads();
        float acc = 0.f;
        for (int j=0; j<L; j++){
            int kkey = sel[wave][j];
            acc += sc[wave][j] * bf2f(Vb[(size_t)kkey*EMBED + h*64 + lane]);
        }
        float o = acc * inv;
        if (!fq) ((u16*)out)[(size_t)q*EMBED + h*64 + lane] = f2b(o);
        else     ((float*)out)[(size_t)q*EMBED + h*64 + lane] = o;
        __syncthreads();
    }
}

// ============ K3: output projection (MFMA), in place on d_out ============
// grid 128: 16 rows/block, staged fully before overwrite.
__global__ __launch_bounds__(256) void oproj_kernel(
    void* __restrict__ out, const void* __restrict__ Wo, const void* __restrict__ bo)
{
    u32 fq = sniffp(out);
    u32 fw = sniffp(Wo), fb = sniffp(bo);
    int r0 = blockIdx.x * 16;
    int t = threadIdx.x;
    __shared__ u16  ab[16*520];
    __shared__ float xf[4][512];

    if (!(fq|fw|fb)){
        {
            int row = t>>4, seg = t&15;
            const uint4* src = (const uint4*)((const u16*)out + (size_t)(r0+row)*EMBED + seg*32);
            uint4* dst = (uint4*)(ab + row*520 + seg*32);
            dst[0] = src[0]; dst[1] = src[1];
        }
        __syncthreads();
        int lane = t&63, wave = t>>6;
        int m = lane&15, quad = lane>>4;
        int obase = wave*128;
        f32x4 acc[8];
        #pragma unroll
        for (int i=0;i<8;i++){ f32x4 z = {0.f,0.f,0.f,0.f}; acc[i] = z; }
        const u16* arow = ab + m*520 + quad*8;
        const u16* wp = (const u16*)Wo;
        for (int k=0;k<16;k++){
            int i0 = k*32;
            s16x8 a = *(const s16x8*)(arow + i0);
            #pragma unroll
            for (int tile=0;tile<8;tile++){
                int o = obase + tile*16 + m;
                s16x8 b = *(const s16x8*)(wp + (size_t)o*EMBED + i0 + quad*8);
                acc[tile] = __builtin_amdgcn_mfma_f32_16x16x32_bf16(a, b, acc[tile], 0, 0, 0);
            }
        }
        #pragma unroll
        for (int tile=0;tile<8;tile++){
            int o = obase + tile*16 + m;
            float bias = bf2f(((const u16*)bo)[o]);
            #pragma unroll
            for (int reg=0;reg<4;reg++){
                int row = quad*4 + reg;
                ((u16*)out)[(size_t)(r0+row)*EMBED + o] = f2b(acc[tile][reg] + bias);
            }
        }
    } else {
        for (int g=0; g<4; g++){
            {
                float* xr = &xf[0][0] + t*8;
                if (!fq){
                    uint4 u = ((const uint4*)((const u16*)out + (size_t)(r0+g*4)*EMBED))[t];
                    xr[0]=lof(u.x); xr[1]=hif(u.x); xr[2]=lof(u.y); xr[3]=hif(u.y);
                    xr[4]=lof(u.z); xr[5]=hif(u.z); xr[6]=lof(u.w); xr[7]=hif(u.w);
                } else {
                    const float4* A4 = (const float4*)((const float*)out + (size_t)(r0+g*4)*EMBED);
                    float4 fa = A4[2*t], fb2 = A4[2*t+1];
                    xr[0]=fa.x; xr[1]=fa.y; xr[2]=fa.z; xr[3]=fa.w;
                    xr[4]=fb2.x; xr[5]=fb2.y; xr[6]=fb2.z; xr[7]=fb2.w;
                }
            }
            __syncthreads();
            float a0[4]={0.f,0.f,0.f,0.f}, a1[4]={0.f,0.f,0.f,0.f};
            if (!fw){
                const uint4* wr0 = (const uint4*)((const u16*)Wo + (size_t)t*EMBED);
                const uint4* wr1 = (const uint4*)((const u16*)Wo + (size_t)(t+256)*EMBED);
                for (int i8=0;i8<64;i8++){
                    uint4 w0 = wr0[i8], w1 = wr1[i8];
                    #pragma unroll
                    for (int r=0;r<4;r++){
                        const float* x = &xf[r][i8*8];
                        fma8(x, w0.x,w0.y,w0.z,w0.w, a0[r]);
                        fma8(x, w1.x,w1.y,w1.z,w1.w, a1[r]);
                    }
                }
            } else {
                const float4* wr0 = (const float4*)((const float*)Wo + (size_t)t*EMBED);
                const float4* wr1 = (const float4*)((const float*)Wo + (size_t)(t+256)*EMBED);
                for (int i4=0;i4<128;i4++){
                    float4 w0 = wr0[i4], w1 = wr1[i4];
                    #pragma unroll
                    for (int r=0;r<4;r++){
                        const float* x = &xf[r][i4*4];
                        fma4f(x, w0, a0[r]);
                        fma4f(x, w1, a1[r]);
                    }
                }
            }
            float b0 = fb ? ((const float*)bo)[t]     : bf2f(((const u16*)bo)[t]);
            float b1 = fb ? ((const float*)bo)[t+256] : bf2f(((const u16*)bo)[t+256]);
            if (!fq){
                u16* o = (u16*)out;
                #pragma unroll
                for (int r=0;r<4;r++){
                    o[(size_t)(r0+g*4+r)*EMBED + t]       = f2b(a0[r]+b0);
                    o[(size_t)(r0+g*4+r)*EMBED + t + 256] = f2b(a1[r]+b1);
                }
            } else {
                float* o = (float*)out;
                #pragma unroll
                for (int r=0;r<4;r++){
                    o[(size_t)(r0+g*4+r)*EMBED + t]       = a0[r]+b0;
                    o[(size_t)(r0+g*4+r)*EMBED + t + 256] = a1[r]+b1;
                }
            }
            __syncthreads();
        }
    }
}

extern "C" void kernel_launch(void* const* d_in, const int* in_sizes, int n_in,
                              void* d_out, int out_size, void* d_ws, size_t ws_size,
                              hipStream_t stream)
{
    const void* query = d_in[0];
    const void* key   = d_in[1];
    const void* value = d_in[2];
    const void* Wq = d_in[3];
    const void* bq = d_in[4];
    const void* Wk = d_in[5];
    const void* bk = d_in[6];
    const void* Wv = d_in[7];
    const void* bv = d_in[8];
    const void* Wo = d_in[9];
    const void* bo = d_in[10];
    const void* cen = d_in[11];

    // ws layout (4,259,840 B total — round-7/8/9-proven footprint):
    //   [0, 32K)        qbin u16[16384]
    //   [32K, 64K)      kbin u16[16384]
    //   [64K, 64K+2M)   Kb bf16 (normalized)
    //   [64K+2M, +2M)   Vb bf16 (raw)
    char* ws = (char*)d_ws;
    u16* qbin = (u16*)ws;
    u16* kbin = (u16*)(ws + 32768);
    u16* Kb   = (u16*)(ws + 65536);
    u16* Vb   = (u16*)(ws + 65536 + (size_t)2*1024*1024);

    projqkv_kernel<<<dim3(128,3), 256, 0, stream>>>(query,key,value,Wq,bq,Wk,bk,Wv,bv,cen,
                                                    d_out,Kb,Vb,qbin,kbin);
    attn_kernel<<<2048, 256, 0, stream>>>(query,Kb,Vb,qbin,kbin,d_out);
    oproj_kernel<<<128, 256, 0, stream>>>(d_out,Wo,bo);
}

// Round 11
// 319.082 us; speedup vs baseline: 3.0250x; 1.3760x over previous
//
#include <hip/hip_runtime.h>
#include <hip/hip_bf16.h>

#define NTOK 2048
#define EMBED 512
#define NHEADS 8
#define HD 64
#define NBINS 512
#define MAXSEL 256

typedef unsigned short u16;
typedef unsigned int u32;

__device__ __forceinline__ float lof(u32 u){ return __uint_as_float(u << 16); }
__device__ __forceinline__ float hif(u32 u){ return __uint_as_float(u & 0xffff0000u); }
__device__ __forceinline__ float bf2f(u16 u){ return __uint_as_float(((u32)u) << 16); }
__device__ __forceinline__ u16 f2b(float f){
    __hip_bfloat16 h = __float2bfloat16(f);
    return *(u16*)&h;
}
__device__ __forceinline__ u32 pack2(float lo, float hi){
    return (u32)f2b(lo) | ((u32)f2b(hi) << 16);
}
__device__ __forceinline__ void fma8(const float* x, u32 ux, u32 uy, u32 uz, u32 uw, float& a){
    a += x[0]*lof(ux) + x[1]*hif(ux) + x[2]*lof(uy) + x[3]*hif(uy)
       + x[4]*lof(uz) + x[5]*hif(uz) + x[6]*lof(uw) + x[7]*hif(uw);
}

// Inline per-block dtype sniff: read 64 even u16s of the tensor as bf16.
// f32 data -> low mantissa halves -> random bf16 exponents -> max>100 w.p. ~1.
// bf16 data here (|x|<6) -> max<10. All threads same samples -> uniform branch.
__device__ __forceinline__ u32 sniffp(const void* p){
    const u16* s = (const u16*)p;
    float m = 0.f;
    #pragma unroll
    for (int k=0; k<64; k++) m = fmaxf(m, fabsf(bf2f(s[2*k])));
    return (m > 100.f) ? 1u : 0u;
}

// ============ K1: QKV projection + per-head norm + centroid bins ============
// grid (256, 3): 8 tokens/block, y: 0=Q 1=K 2=V. block 256 (4 waves).
// Single-pass streaming GEMM: X-tile in LDS (aliases ps), W k-slices through LDS
// with register prefetch. Bins from f32 accumulators (argmax scale-invariant).
__global__ __launch_bounds__(256) void projqkv_kernel(
    const void* __restrict__ Xq, const void* __restrict__ Xk, const void* __restrict__ Xv,
    const void* __restrict__ Wq, const void* __restrict__ bq,
    const void* __restrict__ Wk, const void* __restrict__ bk,
    const void* __restrict__ Wv, const void* __restrict__ bv,
    const void* __restrict__ cen,
    void* __restrict__ outQ,                 // d_out: normalized Q staging (out dtype)
    u16* __restrict__ Kb, u16* __restrict__ Vb,
    u16* __restrict__ qbin, u16* __restrict__ kbin)
{
    int which = blockIdx.y;
    const void *X, *W, *Bb;
    if (which==0){ X=Xq; W=Wq; Bb=bq; }
    else if (which==1){ X=Xk; W=Wk; Bb=bk; }
    else { X=Xv; W=Wv; Bb=bv; }
    u32 fx = sniffp(X), fw = sniffp(W), fb = sniffp(Bb);
    int r0 = blockIdx.x * 8;
    int t = threadIdx.x;

    __shared__ __align__(16) float ubuf[4608];  // wslice [512][9] / scan centT [64][68]
    __shared__ __align__(16) float ps[64*65];   // results [(tok*8+head)][65]; first 4128
                                                // floats alias X-stage [8][516] during GEMM
    __shared__ float nrm2[64][4];
    __shared__ float invn[64];
    __shared__ float bvl[64][8];
    __shared__ int   bil[64][8];

    float* xstage = ps;
    // Phase A: stage X tile (8 x 512), coalesced 16B/lane
    for (int i=t; i<1024; i+=256){
        int row = i>>7, c4 = i&127;
        float4 v;
        if (!fx){
            const u32* xp = (const u32*)((const u16*)X + (size_t)(r0+row)*EMBED);
            u32 a = xp[c4*2], b = xp[c4*2+1];
            v = make_float4(lof(a), hif(a), lof(b), hif(b));
        } else {
            v = ((const float4*)((const float*)X + (size_t)(r0+row)*EMBED))[c4];
        }
        *(float4*)(xstage + row*516 + c4*4) = v;
    }

    float acc2[8][2];
    #pragma unroll
    for (int r=0;r<8;r++){ acc2[r][0]=0.f; acc2[r][1]=0.f; }

    // k-slice loop with register prefetch of the next W slice
    float4 pf[4];
    #pragma unroll
    for (int it=0; it<4; it++){
        int j = t + it*256, o = j>>1, half = j&1;
        if (!fw){
            const u32* wp2 = (const u32*)((const u16*)W + (size_t)o*EMBED + half*4);
            pf[it] = make_float4(lof(wp2[0]), hif(wp2[0]), lof(wp2[1]), hif(wp2[1]));
        } else {
            pf[it] = *(const float4*)((const float*)W + (size_t)o*EMBED + half*4);
        }
    }
    for (int k0=0; k0<512; k0+=8){
        __syncthreads();                 // xstage ready (k0=0) / prev slice consumed
        #pragma unroll
        for (int it=0; it<4; it++){      // write slice: banks 9o%32, conflict-free
            int j = t + it*256, o = j>>1, kb = (j&1)*4;
            ubuf[o*9+kb+0]=pf[it].x; ubuf[o*9+kb+1]=pf[it].y;
            ubuf[o*9+kb+2]=pf[it].z; ubuf[o*9+kb+3]=pf[it].w;
        }
        if (k0+8 < 512){                 // prefetch next slice (overlaps compute)
            int kn = k0+8;
            #pragma unroll
            for (int it=0; it<4; it++){
                int j = t + it*256, o = j>>1, half = j&1;
                if (!fw){
                    const u32* wp2 = (const u32*)((const u16*)W + (size_t)o*EMBED + kn + half*4);
                    pf[it] = make_float4(lof(wp2[0]), hif(wp2[0]), lof(wp2[1]), hif(wp2[1]));
                } else {
                    pf[it] = *(const float4*)((const float*)W + (size_t)o*EMBED + kn + half*4);
                }
            }
        }
        __syncthreads();
        float w0[8], w1[8];
        #pragma unroll
        for (int kk=0;kk<8;kk++){        // b32 reads, lanes t/t+32 share bank: 2-way free
            w0[kk] = ubuf[t*9+kk];
            w1[kk] = ubuf[(t+256)*9+kk];
        }
        #pragma unroll
        for (int r=0;r<8;r++){
            const float* x = xstage + r*516 + k0;   // broadcast b128 reads
            float4 x0 = *(const float4*)(x);
            float4 x1 = *(const float4*)(x+4);
            acc2[r][0] += x0.x*w0[0]+x0.y*w0[1]+x0.z*w0[2]+x0.w*w0[3]
                        + x1.x*w0[4]+x1.y*w0[5]+x1.z*w0[6]+x1.w*w0[7];
            acc2[r][1] += x0.x*w1[0]+x0.y*w1[1]+x0.z*w1[2]+x0.w*w1[3]
                        + x1.x*w1[4]+x1.y*w1[5]+x1.z*w1[6]+x1.w*w1[7];
        }
    }
    __syncthreads();                     // all xstage reads done before ps overwrite
    {
        float b0 = fb ? ((const float*)Bb)[t]     : bf2f(((const u16*)Bb)[t]);
        float b1 = fb ? ((const float*)Bb)[t+256] : bf2f(((const u16*)Bb)[t+256]);
        int h0 = t>>6, c0 = t&63, h1 = (t+256)>>6, c1 = (t+256)&63;
        #pragma unroll
        for (int r=0;r<8;r++){
            ps[(r*8+h0)*65 + c0] = acc2[r][0]+b0;
            ps[(r*8+h1)*65 + c1] = acc2[r][1]+b1;
        }
    }
    __syncthreads();

    if (which == 2){
        // V: store raw bf16, 16 elems/thread
        int hr = t>>2, q4 = t&3;
        int row = hr>>3, head = hr&7;
        const float* src = ps + hr*65 + q4*16;
        u16* dst = Vb + (size_t)(r0+row)*EMBED + head*64 + q4*16;
        #pragma unroll
        for (int j8=0;j8<2;j8++){
            uint4 v;
            v.x = pack2(src[j8*8+0],src[j8*8+1]); v.y = pack2(src[j8*8+2],src[j8*8+3]);
            v.z = pack2(src[j8*8+4],src[j8*8+5]); v.w = pack2(src[j8*8+6],src[j8*8+7]);
            ((uint4*)dst)[j8] = v;
        }
        return;
    }

    // ---------- centroid scan: register-tiled LDS GEMM + argmax, tile prefetch ----------
    u32 fc = sniffp(cen);
    int rg = t>>3, cg = t&7;             // rows {2rg, 2rg+1}, cents cg*8..cg*8+7 per tile
    float best[2] = {-3.4e38f,-3.4e38f};
    int   bidx[2] = {0,0};
    float cpre[16];
    #pragma unroll
    for (int it=0; it<16; it++){
        int e = t + it*256, j = e>>6, k = e&63;
        cpre[it] = fc ? ((const float*)cen)[(size_t)j*HD + k]
                      : bf2f(((const u16*)cen)[(size_t)j*HD + k]);
    }
    for (int tt=0; tt<8; tt++){
        __syncthreads();                 // prev tile consumed (tt=0: ubuf free post-GEMM)
        #pragma unroll
        for (int it=0; it<16; it++){
            int e = t + it*256, j = e>>6, k = e&63;
            ubuf[k*68 + j] = cpre[it];
        }
        if (tt < 7){
            #pragma unroll
            for (int it=0; it<16; it++){
                int e = t + it*256, j = e>>6, k = e&63;
                int gj = (tt+1)*64 + j;
                cpre[it] = fc ? ((const float*)cen)[(size_t)gj*HD + k]
                              : bf2f(((const u16*)cen)[(size_t)gj*HD + k]);
            }
        }
        __syncthreads();
        float acc[2][8];
        #pragma unroll
        for (int j=0;j<2;j++)
            #pragma unroll
            for (int c=0;c<8;c++) acc[j][c]=0.f;
        const float* pr0 = ps + (2*rg)*65;
        const float* pr1 = pr0 + 65;
        for (int k=0;k<64;k++){
            float a0 = pr0[k], a1 = pr1[k];
            const float4* cp = (const float4*)(ubuf + k*68 + cg*8);
            float4 c0 = cp[0], c1 = cp[1];
            acc[0][0]+=a0*c0.x; acc[0][1]+=a0*c0.y; acc[0][2]+=a0*c0.z; acc[0][3]+=a0*c0.w;
            acc[0][4]+=a0*c1.x; acc[0][5]+=a0*c1.y; acc[0][6]+=a0*c1.z; acc[0][7]+=a0*c1.w;
            acc[1][0]+=a1*c0.x; acc[1][1]+=a1*c0.y; acc[1][2]+=a1*c0.z; acc[1][3]+=a1*c0.w;
            acc[1][4]+=a1*c1.x; acc[1][5]+=a1*c1.y; acc[1][6]+=a1*c1.z; acc[1][7]+=a1*c1.w;
        }
        #pragma unroll
        for (int j=0;j<2;j++){
            #pragma unroll
            for (int c=0;c<8;c++){
                int gi = tt*64 + cg*8 + c;   // ascending in-thread -> strict > keeps first
                if (acc[j][c] > best[j]){ best[j]=acc[j][c]; bidx[j]=gi; }
            }
        }
    }
    bvl[2*rg  ][cg]=best[0]; bil[2*rg  ][cg]=bidx[0];
    bvl[2*rg+1][cg]=best[1]; bil[2*rg+1][cg]=bidx[1];
    {
        int hr = t>>2, q4 = t&3;
        const float* src = ps + hr*65 + q4*16;
        float ss=0.f;
        #pragma unroll
        for (int d=0;d<16;d++) ss += src[d]*src[d];
        nrm2[hr][q4]=ss;
    }
    __syncthreads();
    if (t < 64){
        int hr = t;
        invn[hr] = 1.f / fmaxf(sqrtf(nrm2[hr][0]+nrm2[hr][1]+nrm2[hr][2]+nrm2[hr][3]), 1e-12f);
        float bv = bvl[hr][0]; int bi = bil[hr][0];
        #pragma unroll
        for (int g=1; g<8; g++){         // disjoint index sets: (>, ==&&<) merge = np.argmax
            float ov = bvl[hr][g]; int oi = bil[hr][g];
            if (ov > bv || (ov == bv && oi < bi)){ bv = ov; bi = oi; }
        }
        u16* bins = (which==0) ? qbin : kbin;
        int token = r0 + (hr>>3), head = hr&7;
        bins[head*NTOK + token] = (u16)bi;
    }
    __syncthreads();
    {
        int hr = t>>2, q4 = t&3;
        float inv = invn[hr];
        const float* src = ps + hr*65 + q4*16;
        int row = hr>>3, head = hr&7;
        size_t off = (size_t)(r0+row)*EMBED + head*64 + q4*16;
        if (which == 1){
            u16* dst = Kb + off;
            #pragma unroll
            for (int j8=0;j8<2;j8++){
                uint4 v;
                v.x = pack2(src[j8*8+0]*inv, src[j8*8+1]*inv);
                v.y = pack2(src[j8*8+2]*inv, src[j8*8+3]*inv);
                v.z = pack2(src[j8*8+4]*inv, src[j8*8+5]*inv);
                v.w = pack2(src[j8*8+6]*inv, src[j8*8+7]*inv);
                ((uint4*)dst)[j8] = v;
            }
        } else if (!fx){
            u16* dst = (u16*)outQ + off;
            #pragma unroll
            for (int j8=0;j8<2;j8++){
                uint4 v;
                v.x = pack2(src[j8*8+0]*inv, src[j8*8+1]*inv);
                v.y = pack2(src[j8*8+2]*inv, src[j8*8+3]*inv);
                v.z = pack2(src[j8*8+4]*inv, src[j8*8+5]*inv);
                v.w = pack2(src[j8*8+6]*inv, src[j8*8+7]*inv);
                ((uint4*)dst)[j8] = v;
            }
        } else {
            float* dst = (float*)outQ + off;
            #pragma unroll
            for (int j4=0;j4<4;j4++){
                float4 v = make_float4(src[j4*4+0]*inv, src[j4*4+1]*inv,
                                       src[j4*4+2]*inv, src[j4*4+3]*inv);
                ((float4*)dst)[j4] = v;
            }
        }
    }
}

// ============ K2: attention ============
// grid 2048 (one block per query token), 4 waves x 2 heads. Qb read from d_out row q,
// AO written back to the same row (race-free). Wave-level scan, minimal barriers.
__global__ __launch_bounds__(256) void attn_kernel(
    const void* __restrict__ query,
    const u16* __restrict__ Kb, const u16* __restrict__ Vb,
    const u16* __restrict__ qbin, const u16* __restrict__ kbin,
    void* __restrict__ out)
{
    u32 fq = sniffp(query);
    int q = blockIdx.x, t = threadIdx.x;
    int wave = t>>6, lane = t&63;
    __shared__ float qs[512];
    __shared__ float sc[4][256];
    __shared__ u16   sel[4][256];

    if (!fq){
        u32 u = ((const u32*)out)[(size_t)q*256 + t];
        qs[2*t] = lof(u); qs[2*t+1] = hif(u);
    } else {
        float2 f = ((const float2*)out)[(size_t)q*256 + t];
        qs[2*t] = f.x; qs[2*t+1] = f.y;
    }
    __syncthreads();

    for (int hh=0; hh<2; hh++){
        int h = wave*2 + hh;
        int myqb = qbin[h*NTOK + q];
        const uint4* kbp = (const uint4*)(kbin + h*NTOK + lane*32);
        u32 fl = 0;
        #pragma unroll
        for (int w4=0; w4<4; w4++){
            uint4 kw = kbp[w4];
            u32 arr[4] = {kw.x, kw.y, kw.z, kw.w};
            #pragma unroll
            for (int e=0;e<4;e++){
                int b0 = (int)(arr[e] & 0xffff), b1 = (int)(arr[e] >> 16);
                int d0 = (myqb - b0) & (NBINS-1), d1 = (myqb - b1) & (NBINS-1);
                if (d0 <= 1 || d0 >= NBINS-1) fl |= 1u << (w4*8 + e*2);
                if (d1 <= 1 || d1 >= NBINS-1) fl |= 1u << (w4*8 + e*2 + 1);
            }
        }
        int cnt = __popc(fl);
        int sum = cnt;
        #pragma unroll
        for (int off=1; off<64; off<<=1){
            int v = __shfl_up(sum, off, 64);
            if (lane >= off) sum += v;
        }
        int total = __shfl(sum, 63, 64);
        int r = sum - cnt;
        if (total){
            u32 f2 = fl;
            while (f2){
                int j = __ffs(f2) - 1; f2 &= f2 - 1;
                if (r < MAXSEL) sel[wave][r] = (u16)(lane*32 + j);
                r++;
            }
        } else {
            #pragma unroll
            for (int kq=0;kq<4;kq++) sel[wave][lane*4+kq] = (u16)(lane*4+kq);
        }
        int L = total ? min(total, MAXSEL) : MAXSEL;
        __syncthreads();
        const float* qh = qs + h*64;
        float mloc = -3.4e38f;
        for (int jj=lane; jj<L; jj+=64){
            int kkey = sel[wave][jj];
            const uint4* kr = (const uint4*)(Kb + (size_t)kkey*EMBED + h*64);
            float acc = 0.f;
            #pragma unroll
            for (int p=0;p<8;p++){ uint4 u = kr[p]; fma8(qh+p*8, u.x,u.y,u.z,u.w, acc); }
            float s = acc * 0.125f;
            sc[wave][jj] = s;
            mloc = fmaxf(mloc, s);
        }
        #pragma unroll
        for (int off=32; off; off>>=1) mloc = fmaxf(mloc, __shfl_xor(mloc, off, 64));
        float ssum = 0.f;
        for (int jj=lane; jj<L; jj+=64){
            float e = __expf(sc[wave][jj] - mloc);
            sc[wave][jj] = e; ssum += e;
        }
        #pragma unroll
        for (int off=32; off; off>>=1) ssum += __shfl_xor(ssum, off, 64);
        float inv = 1.f / fmaxf(ssum, 1e-37f);
        __syncthreads();
        float acc = 0.f;
        for (int j=0; j<L; j++){
            int kkey = sel[wave][j];
            acc += sc[wave][j] * bf2f(Vb[(size_t)kkey*EMBED + h*64 + lane]);
        }
        float o = acc * inv;
        if (!fq) ((u16*)out)[(size_t)q*EMBED + h*64 + lane] = f2b(o);
        else     ((float*)out)[(size_t)q*EMBED + h*64 + lane] = o;
        __syncthreads();
    }
}

// ============ K3: output projection, in place on d_out ============
// grid 512: 4 rows/block, single-pass streaming W (same pattern as K1).
__global__ __launch_bounds__(256) void oproj_kernel(
    void* __restrict__ out, const void* __restrict__ Wo, const void* __restrict__ bo)
{
    u32 fq = sniffp(out);                 // attn output dtype (== final out dtype)
    u32 fw = sniffp(Wo), fb = sniffp(bo);
    int r0 = blockIdx.x * 4;
    int t = threadIdx.x;
    __shared__ __align__(16) float wsl[512*9];   // 18432 B
    __shared__ __align__(16) float xst[4*516];   // 8256 B

    // stage this block's 4 rows BEFORE any overwrite
    for (int i=t; i<512; i+=256){
        int row = i>>7, c4 = i&127;
        float4 v;
        if (!fq){
            const u32* xp = (const u32*)((const u16*)out + (size_t)(r0+row)*EMBED);
            u32 a = xp[c4*2], b = xp[c4*2+1];
            v = make_float4(lof(a), hif(a), lof(b), hif(b));
        } else {
            v = ((const float4*)((const float*)out + (size_t)(r0+row)*EMBED))[c4];
        }
        *(float4*)(xst + row*516 + c4*4) = v;
    }

    float acc2[4][2];
    #pragma unroll
    for (int r=0;r<4;r++){ acc2[r][0]=0.f; acc2[r][1]=0.f; }

    float4 pf[4];
    #pragma unroll
    for (int it=0; it<4; it++){
        int j = t + it*256, o = j>>1, half = j&1;
        if (!fw){
            const u32* wp2 = (const u32*)((const u16*)Wo + (size_t)o*EMBED + half*4);
            pf[it] = make_float4(lof(wp2[0]), hif(wp2[0]), lof(wp2[1]), hif(wp2[1]));
        } else {
            pf[it] = *(const float4*)((const float*)Wo + (size_t)o*EMBED + half*4);
        }
    }
    for (int k0=0; k0<512; k0+=8){
        __syncthreads();
        #pragma unroll
        for (int it=0; it<4; it++){
            int j = t + it*256, o = j>>1, kb = (j&1)*4;
            wsl[o*9+kb+0]=pf[it].x; wsl[o*9+kb+1]=pf[it].y;
            wsl[o*9+kb+2]=pf[it].z; wsl[o*9+kb+3]=pf[it].w;
        }
        if (k0+8 < 512){
            int kn = k0+8;
            #pragma unroll
            for (int it=0; it<4; it++){
                int j = t + it*256, o = j>>1, half = j&1;
                if (!fw){
                    const u32* wp2 = (const u32*)((const u16*)Wo + (size_t)o*EMBED + kn + half*4);
                    pf[it] = make_float4(lof(wp2[0]), hif(wp2[0]), lof(wp2[1]), hif(wp2[1]));
                } else {
                    pf[it] = *(const float4*)((const float*)Wo + (size_t)o*EMBED + kn + half*4);
                }
            }
        }
        __syncthreads();
        float w0[8], w1[8];
        #pragma unroll
        for (int kk=0;kk<8;kk++){
            w0[kk] = wsl[t*9+kk];
            w1[kk] = wsl[(t+256)*9+kk];
        }
        #pragma unroll
        for (int r=0;r<4;r++){
            const float* x = xst + r*516 + k0;
            float4 x0 = *(const float4*)(x);
            float4 x1 = *(const float4*)(x+4);
            acc2[r][0] += x0.x*w0[0]+x0.y*w0[1]+x0.z*w0[2]+x0.w*w0[3]
                        + x1.x*w0[4]+x1.y*w0[5]+x1.z*w0[6]+x1.w*w0[7];
            acc2[r][1] += x0.x*w1[0]+x0.y*w1[1]+x0.z*w1[2]+x0.w*w1[3]
                        + x1.x*w1[4]+x1.y*w1[5]+x1.z*w1[6]+x1.w*w1[7];
        }
    }
    float b0 = fb ? ((const float*)bo)[t]     : bf2f(((const u16*)bo)[t]);
    float b1 = fb ? ((const float*)bo)[t+256] : bf2f(((const u16*)bo)[t+256]);
    if (!fq){
        u16* o = (u16*)out;
        #pragma unroll
        for (int r=0;r<4;r++){
            o[(size_t)(r0+r)*EMBED + t]       = f2b(acc2[r][0]+b0);
            o[(size_t)(r0+r)*EMBED + t + 256] = f2b(acc2[r][1]+b1);
        }
    } else {
        float* o = (float*)out;
        #pragma unroll
        for (int r=0;r<4;r++){
            o[(size_t)(r0+r)*EMBED + t]       = acc2[r][0]+b0;
            o[(size_t)(r0+r)*EMBED + t + 256] = acc2[r][1]+b1;
        }
    }
}

extern "C" void kernel_launch(void* const* d_in, const int* in_sizes, int n_in,
                              void* d_out, int out_size, void* d_ws, size_t ws_size,
                              hipStream_t stream)
{
    const void* query = d_in[0];
    const void* key   = d_in[1];
    const void* value = d_in[2];
    const void* Wq = d_in[3];
    const void* bq = d_in[4];
    const void* Wk = d_in[5];
    const void* bk = d_in[6];
    const void* Wv = d_in[7];
    const void* bv = d_in[8];
    const void* Wo = d_in[9];
    const void* bo = d_in[10];
    const void* cen = d_in[11];

    // ws layout (4,259,840 B total — proven footprint since round 7):
    //   [0, 32K)        qbin u16[16384]
    //   [32K, 64K)      kbin u16[16384]
    //   [64K, 64K+2M)   Kb bf16 (normalized)
    //   [64K+2M, +2M)   Vb bf16 (raw)
    char* ws = (char*)d_ws;
    u16* qbin = (u16*)ws;
    u16* kbin = (u16*)(ws + 32768);
    u16* Kb   = (u16*)(ws + 65536);
    u16* Vb   = (u16*)(ws + 65536 + (size_t)2*1024*1024);

    projqkv_kernel<<<dim3(256,3), 256, 0, stream>>>(query,key,value,Wq,bq,Wk,bk,Wv,bv,cen,
                                                    d_out,Kb,Vb,qbin,kbin);
    attn_kernel<<<2048, 256, 0, stream>>>(query,Kb,Vb,qbin,kbin,d_out);
    oproj_kernel<<<512, 256, 0, stream>>>(d_out,Wo,bo);
}